// Round 12
// baseline (2065.215 us; speedup 1.0000x reference)
//
#include <hip/hip_runtime.h>
#include <stdint.h>

constexpr int kB   = 64;
constexpr int kTV  = 40;
constexpr int kF   = 2048;
constexpr int kH   = 1024;
constexpr int kV   = 32000;
constexpr int kNS  = 30;
constexpr int kCAP = 31;

typedef __attribute__((ext_vector_type(8))) short bf16x8;
typedef __attribute__((ext_vector_type(4))) float f32x4;
typedef unsigned short us;

__device__ __forceinline__ float sigm(float x) { return 1.f / (1.f + __expf(-x)); }
__device__ __forceinline__ float tanh_fast(float x) {
    float e = __expf(2.f * x);
    return 1.f - 2.f / (e + 1.f);
}
__device__ __forceinline__ us f2bf(float x) {
    unsigned u = __float_as_uint(x);
    return (us)((u + 0x7fffu + ((u >> 16) & 1u)) >> 16);
}
__device__ __forceinline__ float bf2f(us u) {
    return __uint_as_float((unsigned)u << 16);
}

__device__ __forceinline__ void gl16(const us* g, us* lds) {
    __builtin_amdgcn_global_load_lds(
        (const __attribute__((address_space(1))) unsigned int*)(g),
        (__attribute__((address_space(3))) unsigned int*)(lds), 16, 0, 0);
}

template <int N>
__device__ __forceinline__ void waitv() {
    asm volatile("s_waitcnt vmcnt(%0)" :: "n"(N) : "memory");
}
__device__ __forceinline__ void barrier_raw() {
    __builtin_amdgcn_s_barrier();
    asm volatile("" ::: "memory");
}

// A-packed layout: [kt][ms][lane][j]; (row,col): ms=row>>4,
// lane=(row&15)+16*((kc>>2)&3), j=(kc&3)+4*(kc>>4), kc=col&31, kt=col>>5.
__device__ __forceinline__ void store_packedA(us* base, int row, int col, us v) {
    int kt = col >> 5, kc = col & 31, ms = row >> 4;
    int l = (row & 15) + (((kc >> 2) & 3) << 4);
    int j = (kc & 3) + ((kc >> 4) << 2);
    base[((((size_t)kt * 4 + ms) * 64 + l) << 3) + j] = v;
}

// ---------------- 3-deep pipelined MFMA K-loop (one 4-wave group) ----------------
template <int NSPW, int KT>
__device__ __forceinline__ void mfma_kloop(
    const us* __restrict__ Ap, const us* __restrict__ Bp,
    us* Asm, us* Bsm, int w, int l, f32x4 acc[4][NSPW])
{
    constexpr int BSTEP = 2048 * NSPW;
    constexpr int LPT = 1 + NSPW;
    auto stage = [&](int t, int slot) {
        gl16(Ap + (size_t)t * 2048 + w * 512 + l * 8, Asm + slot * 2048 + w * 512);
#pragma unroll
        for (int i = 0; i < NSPW; ++i)
            gl16(Bp + (size_t)t * BSTEP + (w * NSPW + i) * 512 + l * 8,
                 Bsm + slot * BSTEP + (w * NSPW + i) * 512);
    };
    stage(0, 0); stage(1, 1); stage(2, 2);
#pragma unroll 1
    for (int t = 0; t < KT; ++t) {
        int slot = t % 3;
        int rem = KT - 1 - t;
        if (rem >= 2) waitv<2 * LPT>();
        else if (rem == 1) waitv<LPT>();
        else waitv<0>();
        barrier_raw();
        bf16x8 bfr[NSPW], afr[4];
#pragma unroll
        for (int i = 0; i < NSPW; ++i)
            bfr[i] = *(const bf16x8*)(Bsm + slot * BSTEP + ((w * NSPW + i) * 64 + l) * 8);
#pragma unroll
        for (int ms = 0; ms < 4; ++ms)
            afr[ms] = *(const bf16x8*)(Asm + slot * 2048 + (ms * 64 + l) * 8);
#pragma unroll
        for (int ms = 0; ms < 4; ++ms)
#pragma unroll
            for (int i = 0; i < NSPW; ++i)
                acc[ms][i] = __builtin_amdgcn_mfma_f32_16x16x32_bf16(
                    afr[ms], bfr[i], acc[ms][i], 0, 0, 0);
        __builtin_amdgcn_sched_barrier(0);
        barrier_raw();
        if (t + 3 < KT) stage(t + 3, slot);
    }
}

// ---------------- prep: feat mean + bias sums + mask sums ----------------
__global__ __launch_bounds__(256) void prep_mean(
    const float* __restrict__ af, float* __restrict__ fm,
    const float* __restrict__ bih1, const float* __restrict__ bhh1,
    const float* __restrict__ bih2, const float* __restrict__ bhh2,
    const float* __restrict__ capmask,
    float* __restrict__ bsum1, float* __restrict__ bsum2, float* __restrict__ msum)
{
    int tid = threadIdx.x;
    if (blockIdx.x < 64) {
        int b = blockIdx.x;
        const float* base = af + (size_t)b * kTV * kF;
        float a[8] = {};
        for (int t = 0; t < kTV; ++t) {
            const float* rp = base + (size_t)t * kF + tid * 8;
            float4 v0 = *(const float4*)rp;
            float4 v1 = *(const float4*)(rp + 4);
            a[0] += v0.x; a[1] += v0.y; a[2] += v0.z; a[3] += v0.w;
            a[4] += v1.x; a[5] += v1.y; a[6] += v1.z; a[7] += v1.w;
        }
        float* op = fm + (size_t)b * kF + tid * 8;
#pragma unroll
        for (int j = 0; j < 8; ++j) op[j] = a[j] * (1.f / kTV);
    } else {
        int g = (blockIdx.x - 64) * 256 + tid;
        if (g < 4096) bsum1[g] = bih1[g] + bhh1[g];
        else if (g < 8192) { int j = g - 4096; bsum2[j] = bih2[j] + bhh2[j]; }
        else if (g < 8192 + kNS) {
            int t = g - 8192;
            float s = 0.f;
            for (int b = 0; b < kB; ++b) s += capmask[b * kCAP + t + 1];
            msum[t] = s;
        }
    }
}

// ---------------- packing: row-major source(s) -> fragment tiles ----------------
__global__ __launch_bounds__(256) void pack_rm(
    const float* __restrict__ p0, int ld0, int ksplit,
    const float* __restrict__ p1, int ld1,
    int NGRP, int GS, int HS, int KT,
    us* __restrict__ out)
{
    __shared__ us tile[16][136];
    int kb = blockIdx.x * 128;
    int grp = blockIdx.y;
    int row0 = (grp % NGRP) * GS + (grp / NGRP) * HS;
    int tid = threadIdx.x;
    int r = tid >> 5, c4 = (tid & 31) * 4;
#pragma unroll
    for (int pass = 0; pass < 2; ++pass) {
        int rr = r + pass * 8;
        int row = row0 + rr;
        int k = kb + c4;
        float4 v;
        if (k < ksplit) v = *(const float4*)(p0 + (size_t)row * ld0 + k);
        else            v = *(const float4*)(p1 + (size_t)row * ld1 + (k - ksplit));
        ushort4 o; o.x = f2bf(v.x); o.y = f2bf(v.y); o.z = f2bf(v.z); o.w = f2bf(v.w);
        *(ushort4*)&tile[rr][c4] = o;
    }
    __syncthreads();
    int ktl = tid >> 6, l = tid & 63, ul = l & 15, q = (l >> 4) & 3;
    __align__(16) us o2[8];
#pragma unroll
    for (int j = 0; j < 8; ++j) {
        int kc = (j & 3) + q * 4 + ((j >> 2) << 4);
        o2[j] = tile[ul][ktl * 32 + kc];
    }
    int kt = (kb >> 5) + ktl;
    size_t base = (((size_t)(grp / NGRP) * KT + kt) * NGRP + (grp % NGRP)) * 512;
    *(uint4*)(out + base + (size_t)l * 8) = *(const uint4*)o2;
}

// vocab [K][32000] -> B tiles S=8
__global__ __launch_bounds__(256) void pack_cm(const float* __restrict__ W,
                                               us* __restrict__ out)
{
    __shared__ us tile[32][136];
    int n0 = blockIdx.x * 128, k0 = blockIdx.y * 32;
    int tid = threadIdx.x;
    int r = tid >> 5, c4 = (tid & 31) * 4;
#pragma unroll
    for (int pass = 0; pass < 4; ++pass) {
        int rr = r + pass * 8;
        float4 v = *(const float4*)(W + (size_t)(k0 + rr) * kV + n0 + c4);
        ushort4 o; o.x = f2bf(v.x); o.y = f2bf(v.y); o.z = f2bf(v.z); o.w = f2bf(v.w);
        *(ushort4*)&tile[rr][c4] = o;
    }
    __syncthreads();
    int ns = tid >> 5, lp = (tid & 31) * 2;
    size_t base = (((size_t)blockIdx.x * 32 + blockIdx.y) * 8 + ns) * 512;
    __align__(16) us o2[16];
#pragma unroll
    for (int li = 0; li < 2; ++li) {
        int l = lp + li, ul = l & 15, q = (l >> 4) & 3;
#pragma unroll
        for (int j = 0; j < 8; ++j) {
            int kc = (j & 3) + q * 4 + ((j >> 2) << 4);
            o2[li * 8 + j] = tile[kc][ns * 16 + ul];
        }
    }
    *(uint4*)(out + base + lp * 8) = *(const uint4*)&o2[0];
    *(uint4*)(out + base + lp * 8 + 8) = *(const uint4*)&o2[8];
}

// 4 small [K][1024] weights -> B tiles S=4, coalesced LDS-staged
__global__ __launch_bounds__(256) void pack_sm4(
    const float* __restrict__ Wi, const float* __restrict__ Wm,
    const float* __restrict__ Wua, const float* __restrict__ Wa,
    us* __restrict__ oi, us* __restrict__ om,
    us* __restrict__ oua, us* __restrict__ oa)
{
    int bid = blockIdx.x;
    const float* W; us* out; int KT, rel;
    if (bid < 512)       { W = Wi;  out = oi;  KT = 64; rel = bid; }
    else if (bid < 1024) { W = Wm;  out = om;  KT = 64; rel = bid - 512; }
    else if (bid < 1280) { W = Wua; out = oua; KT = 32; rel = bid - 1024; }
    else                 { W = Wa;  out = oa;  KT = 32; rel = bid - 1280; }
    int bx = rel & 7, by = rel >> 3;
    __shared__ us tile[32][136];
    int n0 = bx * 128, k0 = by * 32;
    int tid = threadIdx.x;
    int r = tid >> 5, c4 = (tid & 31) * 4;
#pragma unroll
    for (int pass = 0; pass < 4; ++pass) {
        int rr = r + pass * 8;
        float4 v = *(const float4*)(W + (size_t)(k0 + rr) * 1024 + n0 + c4);
        ushort4 o; o.x = f2bf(v.x); o.y = f2bf(v.y); o.z = f2bf(v.z); o.w = f2bf(v.w);
        *(ushort4*)&tile[rr][c4] = o;
    }
    __syncthreads();
    int ns = tid >> 5, lp = (tid & 31) * 2;
    int nb64 = bx * 2 + (ns >> 2), ns4 = ns & 3;
    size_t base = (((size_t)nb64 * KT + by) * 4 + ns4) * 512;
    __align__(16) us o2[16];
#pragma unroll
    for (int li = 0; li < 2; ++li) {
        int l = lp + li, ul = l & 15, q = (l >> 4) & 3;
#pragma unroll
        for (int j = 0; j < 8; ++j) {
            int kc = (j & 3) + q * 4 + ((j >> 2) << 4);
            o2[li * 8 + j] = tile[kc][ns * 16 + ul];
        }
    }
    *(uint4*)(out + base + lp * 8) = *(const uint4*)&o2[0];
    *(uint4*)(out + base + lp * 8 + 8) = *(const uint4*)&o2[8];
}

// Wa -> WaE[nb][cb][ns][64][8]: K=32 B-frags, k 0-15 = Wa rows nb*16+k, k>=16 zero
__global__ __launch_bounds__(256) void pack_wae(const float* __restrict__ Wa,
                                                us* __restrict__ WaE)
{
    int nb = blockIdx.x >> 4, cb = blockIdx.x & 15;
    int tid = threadIdx.x;
    int ns = tid >> 6, l = tid & 63;
    int ul = l & 15, q = (l >> 4) & 3;
    int col = cb * 64 + ns * 16 + ul;
    __align__(16) us o[8];
#pragma unroll
    for (int j = 0; j < 4; ++j) {
        int k = (j & 3) + q * 4;               // 0..15
        o[j] = f2bf(Wa[(size_t)(nb * 16 + k) * kH + col]);
    }
    o[4] = 0; o[5] = 0; o[6] = 0; o[7] = 0;
    size_t base = (((size_t)(nb * 16 + cb)) * 4 + ns) * 512;
    *(uint4*)(WaE + base + (size_t)l * 8) = *(const uint4*)o;
}

// per-step emb rows -> A-packed tiles: embP[s][kt32][ms4][512]
__global__ __launch_bounds__(256) void pack_emb(
    const float* __restrict__ Wemb, const int* __restrict__ captions,
    us* __restrict__ embP)
{
    __shared__ us tile[16][136];
    int rel = blockIdx.x;              // 960 = 30 s x 4 rg x 8 kb
    int s = rel / 32, rem = rel % 32;
    int rg = rem & 3, kb8 = rem >> 2;
    int tid = threadIdx.x;
    int r = tid >> 5, c4 = (tid & 31) * 4;
#pragma unroll
    for (int pass = 0; pass < 2; ++pass) {
        int rr = r + pass * 8;
        int b = rg * 16 + rr;
        int word = captions[b * kCAP + s];
        float4 v = *(const float4*)(Wemb + (size_t)word * kH + kb8 * 128 + c4);
        ushort4 o; o.x = f2bf(v.x); o.y = f2bf(v.y); o.z = f2bf(v.z); o.w = f2bf(v.w);
        *(ushort4*)&tile[rr][c4] = o;
    }
    __syncthreads();
    int ktl = tid >> 6, l = tid & 63, ul = l & 15, q = (l >> 4) & 3;
    __align__(16) us o2[8];
#pragma unroll
    for (int j = 0; j < 8; ++j) {
        int kc = (j & 3) + q * 4 + ((j >> 2) << 4);
        o2[j] = tile[ul][ktl * 32 + kc];
    }
    int kt = kb8 * 4 + ktl;
    size_t base = (((size_t)s * 32 + kt) * 4 + rg) * 512;
    *(uint4*)(embP + base + (size_t)l * 8) = *(const uint4*)o2;
}

// ---------------- encoder GEMM (LDS-staged), bf16 outF ----------------
template <int KT>
__global__ __launch_bounds__(256) void enc_gemm(
    const us* __restrict__ Ap, const us* __restrict__ Bp,
    const float* __restrict__ bias, us* __restrict__ outF,
    us* __restrict__ outP)
{
    __shared__ us Asm[3][2048];
    __shared__ us Bsm[3][2048];
    int tid = threadIdx.x, w = tid >> 6, l = tid & 63;
    int nb = blockIdx.x, mb = blockIdx.y;
    f32x4 acc[4][1] = {};
    mfma_kloop<1, KT>(Ap + (size_t)mb * KT * 2048, Bp + (size_t)nb * KT * 2048,
                      &Asm[0][0], &Bsm[0][0], w, l, acc);
    int ul = l & 15, sg = l >> 4;
    int n = nb * 64 + w * 16 + ul;
    float bv = bias[n];
#pragma unroll
    for (int ms = 0; ms < 4; ++ms)
#pragma unroll
        for (int r = 0; r < 4; ++r) {
            int rl = ms * 16 + sg * 4 + r;
            int row = mb * 64 + rl;
            float v = acc[ms][0][r] + bv;
            outF[(size_t)row * kH + n] = f2bf(v);
            if (outP) store_packedA(outP + (size_t)mb * 65536, rl, n, f2bf(v));
        }
}

// P3: feat_h -> x1p0 h1-slot (col 1024+) and h2hist[0]
__global__ __launch_bounds__(256) void p3_gemm(
    const us* __restrict__ Ap, const us* __restrict__ Bp,
    const float* __restrict__ bias, us* __restrict__ xcat1p,
    us* __restrict__ h2hist0)
{
    __shared__ us Asm[3][2048];
    __shared__ us Bsm[3][2048];
    int tid = threadIdx.x, w = tid >> 6, l = tid & 63;
    int nb = blockIdx.x;
    f32x4 acc[4][1] = {};
    mfma_kloop<1, 64>(Ap, Bp + (size_t)nb * 64 * 2048, &Asm[0][0], &Bsm[0][0], w, l, acc);
    int ul = l & 15, sg = l >> 4;
    int n = nb * 64 + w * 16 + ul;
    float bv = bias[n];
#pragma unroll
    for (int ms = 0; ms < 4; ++ms)
#pragma unroll
        for (int r = 0; r < 4; ++r) {
            int row = ms * 16 + sg * 4 + r;
            us hb = f2bf(acc[ms][0][r] + bv);
            store_packedA(xcat1p, row, 1024 + n, hb);
            store_packedA(h2hist0, row, n, hb);
        }
}

// Gemb[s] = emb(s) @ W1ih[:, 0:1024] (bf16 out, gate-interleaved cols)
__global__ __launch_bounds__(256) void gemb_gemm(
    const us* __restrict__ embP, const us* __restrict__ W1p,
    us* __restrict__ Gemb)
{
    __shared__ us Asm[3][2048];
    __shared__ us Bsm[3][2048];
    int rel = blockIdx.x;              // 1920 = 30 s x 64 nb
    int s = rel >> 6, nb = rel & 63;
    int tid = threadIdx.x, w = tid >> 6, l = tid & 63;
    f32x4 acc[4][1] = {};
    mfma_kloop<1, 32>(embP + (size_t)s * 65536, W1p + (size_t)nb * 96 * 2048,
                      &Asm[0][0], &Bsm[0][0], w, l, acc);
    int ul = l & 15, sg = l >> 4;
    int n = nb * 64 + w * 16 + ul;
#pragma unroll
    for (int ms = 0; ms < 4; ++ms)
#pragma unroll
        for (int r = 0; r < 4; ++r) {
            int row = ms * 16 + sg * 4 + r;
            Gemb[((size_t)s * 64 + row) * 4096 + n] = f2bf(acc[ms][0][r]);
        }
}

// ---------------- hwa for s=0 only: hw = h2hist[0] @ att_Wa ----------------
__global__ __launch_bounds__(512) void hwa_gemm(
    const us* __restrict__ h2p, const us* __restrict__ WaP,
    float* __restrict__ hw)
{
    __shared__ __align__(16) char smem[49152];
    float* rsum = (float*)smem;
    int tid = threadIdx.x, w = tid >> 6, l = tid & 63, nb = blockIdx.x;
    int h = w >> 2, w4 = w & 3;
    us* Asm = (us*)(smem + h * 24576);
    us* Bsm = Asm + 6144;
    f32x4 acc[4][1] = {};
    mfma_kloop<1, 16>(h2p + (size_t)h * 16 * 2048,
                      WaP + (size_t)nb * 32 * 2048 + (size_t)h * 16 * 2048,
                      Asm, Bsm, w4, l, acc);
    int ul = l & 15, sg = l >> 4;
    __syncthreads();
    if (h == 1) {
#pragma unroll
        for (int ms = 0; ms < 4; ++ms)
#pragma unroll
            for (int r = 0; r < 4; ++r)
                rsum[((w4 * 64) + ms * 16 + sg * 4 + r) * 17 + ul] = acc[ms][0][r];
    }
    __syncthreads();
    if (h == 0) {
        int n = nb * 64 + w4 * 16 + ul;
#pragma unroll
        for (int ms = 0; ms < 4; ++ms)
#pragma unroll
            for (int r = 0; r < 4; ++r) {
                int row = ms * 16 + sg * 4 + r;
                hw[(size_t)row * kH + n] =
                    acc[ms][0][r] + rsum[((w4 * 64) + row) * 17 + ul];
            }
    }
}

// ---------------- fused attention (per batch row; reduces bf16 hwPart) ----------------
__global__ __launch_bounds__(256) void attn_fused(
    const float* __restrict__ hw0, const us* __restrict__ hwP,
    const us* __restrict__ imgp, const float* __restrict__ attw,
    const us* __restrict__ vf, const float* __restrict__ vmask,
    us* __restrict__ xcat1p)
{
    __shared__ float hwv[kH];
    __shared__ float es[48];
    int b = blockIdx.x, tid = threadIdx.x;
    if (hw0) {
        for (int i = tid; i < kH; i += 256) hwv[i] = hw0[(size_t)b * kH + i];
    } else {
        int c4 = tid * 4;
        float a0 = 0.f, a1 = 0.f, a2 = 0.f, a3 = 0.f;
        for (int nb = 0; nb < 64; ++nb) {
            ushort4 v = *(const ushort4*)(hwP + ((size_t)nb * 64 + b) * 1024 + c4);
            a0 += bf2f(v.x); a1 += bf2f(v.y); a2 += bf2f(v.z); a3 += bf2f(v.w);
        }
        hwv[c4 + 0] = a0; hwv[c4 + 1] = a1; hwv[c4 + 2] = a2; hwv[c4 + 3] = a3;
    }
    __syncthreads();
    int w = tid >> 6, l = tid & 63;
    for (int t = w; t < kTV; t += 4) {
        const us* ip = imgp + ((size_t)b * kTV + t) * kH;
        float p = 0.f;
#pragma unroll
        for (int hh = 0; hh < 16; ++hh) {
            int h = hh * 64 + l;
            p += tanh_fast(hwv[h] + bf2f(ip[h])) * attw[h];
        }
        for (int off = 32; off; off >>= 1) p += __shfl_down(p, off);
        if (l == 0) es[t] = p;
    }
    __syncthreads();
    float mx = -1e30f;
    for (int t = 0; t < kTV; ++t) mx = fmaxf(mx, es[t]);
    const float* vm = vmask + b * kTV;
    float den = 0.f;
    for (int t = 0; t < kTV; ++t) den += vm[t] * __expf(es[t] - mx);
    den = den + (den == 0.f ? 1.f : 0.f) + 1e-9f;
    int h0 = tid * 4;
    float a0 = 0.f, a1 = 0.f, a2 = 0.f, a3 = 0.f;
    for (int t = 0; t < kTV; ++t) {
        float wgt = vm[t] * __expf(es[t] - mx) / den;
        ushort4 v = *(const ushort4*)(vf + ((size_t)b * kTV + t) * kH + h0);
        a0 += wgt * bf2f(v.x); a1 += wgt * bf2f(v.y);
        a2 += wgt * bf2f(v.z); a3 += wgt * bf2f(v.w);
    }
    store_packedA(xcat1p, b, h0 + 0, f2bf(a0));
    store_packedA(xcat1p, b, h0 + 1, f2bf(a1));
    store_packedA(xcat1p, b, h0 + 2, f2bf(a2));
    store_packedA(xcat1p, b, h0 + 3, f2bf(a3));
}

// ---------------- gates1: GEMM + LSTM cell (1024 thr, staged 4-way K-split) ----------------
template <int KT, int BSTR, int KOFF>
__global__ __launch_bounds__(1024) void gates_cell(
    const us* __restrict__ Ap, const us* __restrict__ Bp,
    const float* __restrict__ bsum, const us* __restrict__ gemb,
    float* __restrict__ cbuf,
    us* __restrict__ dA, int ofsA, us* __restrict__ dB, int ofsB)
{
    __shared__ __align__(16) char smem[98304];
    float* gsm = (float*)smem;
    constexpr int KQ = KT / 4;
    int tid = threadIdx.x, w16 = tid >> 6, l = tid & 63, nb = blockIdx.x;
    int g = w16 >> 2, w4 = w16 & 3;
    us* Asm = (us*)(smem + g * 24576);
    us* Bsm = Asm + 6144;
    f32x4 acc[4][1] = {};
    mfma_kloop<1, KQ>(Ap + (size_t)g * KQ * 2048,
                      Bp + (size_t)nb * BSTR * 2048 + (size_t)(KOFF + g * KQ) * 2048,
                      Asm, Bsm, w4, l, acc);
    int ul = l & 15, sg = l >> 4;
    int sl = (g & 1) * 4 + w4;
    float bv = (g == 0) ? bsum[w4 * 1024 + nb * 16 + ul] : 0.f;
    __syncthreads();
    if (g < 2) {
#pragma unroll
        for (int ms = 0; ms < 4; ++ms)
#pragma unroll
            for (int r = 0; r < 4; ++r)
                gsm[(sl * 64 + ms * 16 + sg * 4 + r) * 17 + ul] = acc[ms][0][r] + bv;
    }
    __syncthreads();
    if (g >= 2) {
#pragma unroll
        for (int ms = 0; ms < 4; ++ms)
#pragma unroll
            for (int r = 0; r < 4; ++r)
                gsm[(sl * 64 + ms * 16 + sg * 4 + r) * 17 + ul] += acc[ms][0][r];
    }
    __syncthreads();
    {
        int row = tid >> 4, uc = tid & 15, u = nb * 16 + uc;
        float ge0 = 0.f, ge1 = 0.f, ge2 = 0.f, ge3 = 0.f;
        if (gemb) {
            const us* gp = gemb + (size_t)row * 4096 + nb * 64 + uc;
            ge0 = bf2f(gp[0]); ge1 = bf2f(gp[16]);
            ge2 = bf2f(gp[32]); ge3 = bf2f(gp[48]);
        }
        float gi = gsm[((0 * 64) + row) * 17 + uc] + gsm[((4 * 64) + row) * 17 + uc] + ge0;
        float gf = gsm[((1 * 64) + row) * 17 + uc] + gsm[((5 * 64) + row) * 17 + uc] + ge1;
        float gg = gsm[((2 * 64) + row) * 17 + uc] + gsm[((6 * 64) + row) * 17 + uc] + ge2;
        float go = gsm[((3 * 64) + row) * 17 + uc] + gsm[((7 * 64) + row) * 17 + uc] + ge3;
        float c = sigm(gf) * cbuf[(size_t)row * kH + u] + sigm(gi) * tanh_fast(gg);
        cbuf[(size_t)row * kH + u] = c;
        us hb = f2bf(sigm(go) * tanh_fast(c));
        store_packedA(dA, row, ofsA + u, hb);
        store_packedA(dB, row, ofsB + u, hb);
    }
}

// ---------------- gates2: GEMM + cell + distributed-hwa partial epilogue (bf16) ----------------
__global__ __launch_bounds__(1024) void gates2_cell(
    const us* __restrict__ Ap, const us* __restrict__ Bp,
    const float* __restrict__ bsum, float* __restrict__ cbuf,
    us* __restrict__ dA, int ofsA, us* __restrict__ dB, int ofsB,
    us* __restrict__ hwPart, const us* __restrict__ WaE)
{
    __shared__ __align__(16) char smem[98304];
    float* gsm = (float*)smem;
    us* hA = (us*)(smem + 40960);
    constexpr int KQ = 16;
    int tid = threadIdx.x, w16 = tid >> 6, l = tid & 63, nb = blockIdx.x;
    int g = w16 >> 2, w4 = w16 & 3;
    us* Asm = (us*)(smem + g * 24576);
    us* Bsm = Asm + 6144;
    f32x4 acc[4][1] = {};
    mfma_kloop<1, KQ>(Ap + (size_t)g * KQ * 2048,
                      Bp + (size_t)nb * 64 * 2048 + (size_t)(g * KQ) * 2048,
                      Asm, Bsm, w4, l, acc);
    int ul = l & 15, sg = l >> 4;
    int sl = (g & 1) * 4 + w4;
    float bv = (g == 0) ? bsum[w4 * 1024 + nb * 16 + ul] : 0.f;
    __syncthreads();
    if (g < 2) {
#pragma unroll
        for (int ms = 0; ms < 4; ++ms)
#pragma unroll
            for (int r = 0; r < 4; ++r)
                gsm[(sl * 64 + ms * 16 + sg * 4 + r) * 17 + ul] = acc[ms][0][r] + bv;
    }
    __syncthreads();
    if (g >= 2) {
#pragma unroll
        for (int ms = 0; ms < 4; ++ms)
#pragma unroll
            for (int r = 0; r < 4; ++r)
                gsm[(sl * 64 + ms * 16 + sg * 4 + r) * 17 + ul] += acc[ms][0][r];
    }
    __syncthreads();
    int row = tid >> 4, uc = tid & 15, u = nb * 16 + uc;
    {
        float gi = gsm[((0 * 64) + row) * 17 + uc] + gsm[((4 * 64) + row) * 17 + uc];
        float gf = gsm[((1 * 64) + row) * 17 + uc] + gsm[((5 * 64) + row) * 17 + uc];
        float gg = gsm[((2 * 64) + row) * 17 + uc] + gsm[((6 * 64) + row) * 17 + uc];
        float go = gsm[((3 * 64) + row) * 17 + uc] + gsm[((7 * 64) + row) * 17 + uc];
        float c = sigm(gf) * cbuf[(size_t)row * kH + u] + sigm(gi) * tanh_fast(gg);
        cbuf[(size_t)row * kH + u] = c;
        us hb = f2bf(sigm(go) * tanh_fast(c));
        store_packedA(dA, row, ofsA + u, hb);
        store_packedA(dB, row, ofsB + u, hb);
        if (hwPart) {
            *(unsigned*)(hA + tid * 2) = 0;
            __syncthreads();
            int lpos = (row & 15) + (((uc >> 2) & 3) << 4);
            hA[((((row >> 4) * 64) + lpos) << 3) + (uc & 3)] = hb;
            __syncthreads();
            int cb = w16;
            f32x4 hacc[4][4] = {};
            bf16x8 afr[4];
#pragma unroll
            for (int ms = 0; ms < 4; ++ms)
                afr[ms] = *(const bf16x8*)(hA + (ms * 64 + l) * 8);
#pragma unroll
            for (int ns = 0; ns < 4; ++ns) {
                bf16x8 bfr = *(const bf16x8*)(WaE +
                    ((((size_t)(nb * 16 + cb)) * 4 + ns) << 9) + l * 8);
#pragma unroll
                for (int ms = 0; ms < 4; ++ms)
                    hacc[ms][ns] = __builtin_amdgcn_mfma_f32_16x16x32_bf16(
                        afr[ms], bfr, hacc[ms][ns], 0, 0, 0);
            }
#pragma unroll
            for (int ms = 0; ms < 4; ++ms)
#pragma unroll
                for (int ns = 0; ns < 4; ++ns)
#pragma unroll
                    for (int r = 0; r < 4; ++r) {
                        int row2 = ms * 16 + sg * 4 + r;
                        int col = cb * 64 + ns * 16 + ul;
                        hwPart[((size_t)nb * 64 + row2) * 1024 + col] =
                            f2bf(hacc[ms][ns][r]);
                    }
        }
    }
}

// ---------------- deferred logits: 3 steps/block, 2-slot x 2-kt staged, XCD-grouped ----------------
__global__ __launch_bounds__(256) void logits_sb(
    const us* __restrict__ h2hist, const us* __restrict__ WvP,
    const float* __restrict__ embb, const int* __restrict__ captions,
    float* __restrict__ psumP, float* __restrict__ tlogs)
{
    constexpr int SBLK = 3;
    __shared__ us Asm[SBLK][2][4096];   // [si][slot][2 kt x 2048]
    __shared__ us Bsm[2][8192];         // [slot][2 kt x 4096]
    __shared__ float rsum[4][64];
    __shared__ int stgt[SBLK][64];
    int bid = blockIdx.x;
    int c = bid & 7, q = bid >> 3;
    int sgrp = q % 10, nb = c + (q / 10) * 8;
    if (nb >= 250) return;
    int s0 = sgrp * SBLK;
    int tid = threadIdx.x, w = tid >> 6, l = tid & 63, ul = l & 15, lsg = l >> 4;
    if (tid < 64)
#pragma unroll
        for (int si = 0; si < SBLK; ++si)
            stgt[si][tid] = captions[tid * kCAP + s0 + si + 1];
    const us* Ab0 = h2hist + (size_t)(s0 + 1) * 65536;
    const us* Ab1 = h2hist + (size_t)(s0 + 2) * 65536;
    const us* Ab2 = h2hist + (size_t)(s0 + 3) * 65536;
    const us* Bb  = WvP + (size_t)nb * 32 * 4096;
    auto stage = [&](int it, int slot) {
#pragma unroll
        for (int kk = 0; kk < 2; ++kk) {
            int t = it * 2 + kk;
            gl16(Ab0 + (size_t)t * 2048 + w * 512 + l * 8,
                 &Asm[0][slot][kk * 2048 + w * 512]);
            gl16(Ab1 + (size_t)t * 2048 + w * 512 + l * 8,
                 &Asm[1][slot][kk * 2048 + w * 512]);
            gl16(Ab2 + (size_t)t * 2048 + w * 512 + l * 8,
                 &Asm[2][slot][kk * 2048 + w * 512]);
#pragma unroll
            for (int i = 0; i < 2; ++i)
                gl16(Bb + (size_t)t * 4096 + (w * 2 + i) * 512 + l * 8,
                     &Bsm[slot][kk * 4096 + (w * 2 + i) * 512]);
        }
    };
    f32x4 acc[SBLK][4][2] = {};
    stage(0, 0); stage(1, 1);
#pragma unroll 1
    for (int it = 0; it < 16; ++it) {
        int slot = it & 1;
        if (it < 15) waitv<10>();
        else waitv<0>();
        barrier_raw();
#pragma unroll
        for (int kk = 0; kk < 2; ++kk) {
            bf16x8 b0 = *(const bf16x8*)&Bsm[slot][kk * 4096 + ((w * 2 + 0) * 64 + l) * 8];
            bf16x8 b1 = *(const bf16x8*)&Bsm[slot][kk * 4096 + ((w * 2 + 1) * 64 + l) * 8];
#pragma unroll
            for (int ms = 0; ms < 4; ++ms)
#pragma unroll
                for (int si = 0; si < SBLK; ++si) {
                    bf16x8 a = *(const bf16x8*)&Asm[si][slot][kk * 2048 + (ms * 64 + l) * 8];
                    acc[si][ms][0] = __builtin_amdgcn_mfma_f32_16x16x32_bf16(
                        a, b0, acc[si][ms][0], 0, 0, 0);
                    acc[si][ms][1] = __builtin_amdgcn_mfma_f32_16x16x32_bf16(
                        a, b1, acc[si][ms][1], 0, 0, 0);
                }
        }
        __builtin_amdgcn_sched_barrier(0);
        barrier_raw();
        if (it + 2 < 16) stage(it + 2, slot);
    }
    int n0 = nb * 128 + (2 * w + 0) * 16 + ul;
    int n1 = nb * 128 + (2 * w + 1) * 16 + ul;
    float e0 = embb[n0], e1 = embb[n1];
#pragma unroll
    for (int si = 0; si < SBLK; ++si) {
        float ls[4][4];
#pragma unroll
        for (int ms = 0; ms < 4; ++ms)
#pragma unroll
            for (int r = 0; r < 4; ++r) {
                int row = ms * 16 + lsg * 4 + r;
                float v0 = acc[si][ms][0][r] + e0, v1 = acc[si][ms][1][r] + e1;
                ls[ms][r] = __expf(v0) + __expf(v1);
                if (n0 == stgt[si][row]) tlogs[(s0 + si) * 64 + row] = v0;
                if (n1 == stgt[si][row]) tlogs[(s0 + si) * 64 + row] = v1;
            }
#pragma unroll
        for (int m = 1; m < 16; m <<= 1)
#pragma unroll
            for (int ms = 0; ms < 4; ++ms)
#pragma unroll
                for (int r = 0; r < 4; ++r)
                    ls[ms][r] += __shfl_xor(ls[ms][r], m);
        if (ul == 0)
#pragma unroll
            for (int ms = 0; ms < 4; ++ms)
#pragma unroll
                for (int r = 0; r < 4; ++r)
                    rsum[w][ms * 16 + lsg * 4 + r] = ls[ms][r];
        __syncthreads();
        if (tid < 64)
            psumP[((size_t)(s0 + si) * 250 + nb) * 64 + tid] =
                rsum[0][tid] + rsum[1][tid] + rsum[2][tid] + rsum[3][tid];
        __syncthreads();
    }
}

// ---------------- final loss over all steps ----------------
__global__ __launch_bounds__(256) void final_loss(
    const float* __restrict__ psumP, const float* __restrict__ tlogs,
    const float* __restrict__ msum, float* __restrict__ out)
{
    __shared__ float sl[16000];
    int s = blockIdx.x, tid = threadIdx.x;
    const float* src = psumP + (size_t)s * 16000;
    for (int i = tid; i < 16000; i += 256) sl[i] = src[i];
    __syncthreads();
    if (tid < 64) {
        float tot = 0.f;
        for (int i = 0; i < 250; ++i) tot += sl[i * 64 + tid];
        float logp = tlogs[s * 64 + tid] - __logf(tot);
        float term = -logp * msum[s] * (1.f / 4096.f);
        for (int off = 32; off; off >>= 1) term += __shfl_down(term, off);
        if (tid == 0) atomicAdd(out, term);
    }
}

// ---------------- host ----------------
extern "C" void kernel_launch(void* const* d_in, const int* in_sizes, int n_in,
                              void* d_out, int out_size, void* d_ws, size_t ws_size,
                              hipStream_t stream)
{
    const float* action_feat = (const float*)d_in[1];
    const float* video_mask  = (const float*)d_in[3];
    const int*   captions    = (const int*)d_in[4];
    const float* capmask     = (const float*)d_in[5];
    const float* enc_img_W   = (const float*)d_in[6];
    const float* enc_img_b   = (const float*)d_in[7];
    const float* enc_mean_W  = (const float*)d_in[8];
    const float* enc_mean_b  = (const float*)d_in[9];
    const float* att_w       = (const float*)d_in[10];
    const float* att_Wa      = (const float*)d_in[11];
    const float* att_Ua      = (const float*)d_in[12];
    const float* att_ba      = (const float*)d_in[13];
    const float* Wemb        = (const float*)d_in[14];
    const float* embW        = (const float*)d_in[15];
    const float* embb        = (const float*)d_in[16];
    const float* W1ih        = (const float*)d_in[17];
    const float* W1hh        = (const float*)d_in[18];
    const float* b1ih        = (const float*)d_in[19];
    const float* b1hh        = (const float*)d_in[20];
    const float* W2ih        = (const float*)d_in[21];
    const float* W2hh        = (const float*)d_in[22];
    const float* b2ih        = (const float*)d_in[23];
    const float* b2hh        = (const float*)d_in[24];

    char* base = (char*)d_ws;
    size_t off = 0;
    auto alloc = [&](size_t bytes) {
        char* p = base + off;
        off = (off + bytes + 255) & ~(size_t)255;
        return p;
    };
    constexpr int BIG = 0x40000000;

    us* vf       = (us*)alloc((size_t)2560 * 1024 * 2);
    us* imgp     = (us*)alloc((size_t)2560 * 1024 * 2);
    float* fm    = (float*)alloc((size_t)64 * 2048 * 4);
    float* hw    = (float*)alloc((size_t)64 * 1024 * 4);
    us* hwPart   = (us*)alloc((size_t)64 * 64 * 1024 * 2);
    float* bsum1 = (float*)alloc(4096 * 4);
    float* bsum2 = (float*)alloc(4096 * 4);
    float* msum  = (float*)alloc(32 * 4);
    float* psumP = (float*)alloc((size_t)kNS * 250 * 64 * 4);
    float* tlogs = (float*)alloc((size_t)kNS * 64 * 4);
    us* Gemb     = (us*)alloc((size_t)kNS * 64 * 4096 * 2);
    // zero-init block: x2p[2], c1, c2 contiguous
    us* x2p0 = (us*)alloc((size_t)64 * 2048 * 2);
    us* x2p1 = (us*)alloc((size_t)64 * 2048 * 2);
    float* c1    = (float*)alloc((size_t)64 * 1024 * 4);
    float* c2    = (float*)alloc((size_t)64 * 1024 * 4);
    size_t zlen  = (size_t)((char*)(c2 + 64 * 1024) - (char*)x2p0);

    us* x1p0 = (us*)alloc((size_t)64 * 2048 * 2);
    us* x1p1 = (us*)alloc((size_t)64 * 2048 * 2);
    us* h2hist = (us*)alloc((size_t)(kNS + 1) * 64 * 1024 * 2);
    us* embP = (us*)alloc((size_t)kNS * 64 * 1024 * 2);
    us* afP  = (us*)alloc((size_t)2560 * 2048 * 2);
    us* vfP  = (us*)alloc((size_t)2560 * 1024 * 2);
    us* fmP  = (us*)alloc((size_t)64 * 2048 * 2);
    us* WiP  = (us*)alloc((size_t)2048 * 1024 * 2);
    us* WmP  = (us*)alloc((size_t)2048 * 1024 * 2);
    us* WuaP = (us*)alloc((size_t)1024 * 1024 * 2);
    us* WaP  = (us*)alloc((size_t)1024 * 1024 * 2);
    us* WaE  = (us*)alloc((size_t)64 * 16 * 4 * 512 * 2);
    us* W1p  = (us*)alloc((size_t)3072 * 4096 * 2);
    us* W2p  = (us*)alloc((size_t)2048 * 4096 * 2);
    us* WvP  = (us*)alloc((size_t)1024 * 32000 * 2);
    if (off > ws_size) return;

    hipMemsetAsync(d_out, 0, 4, stream);
    hipMemsetAsync(x2p0, 0, zlen, stream);

    prep_mean<<<97, 256, 0, stream>>>(action_feat, fm, b1ih, b1hh, b2ih, b2hh,
                                      capmask, bsum1, bsum2, msum);
    pack_rm<<<dim3(16, 4), 256, 0, stream>>>(fm, 2048, BIG, nullptr, 0,
                                             4, 16, 64, 64, fmP);
    pack_rm<<<dim3(16, 160), 256, 0, stream>>>(action_feat, 2048, BIG, nullptr, 0,
                                               4, 16, 64, 64, afP);
    pack_rm<<<dim3(24, 256), 256, 0, stream>>>(W1ih, 2048, 2048, W1hh, 1024,
                                               4, 1024, 16, 96, W1p);
    pack_rm<<<dim3(16, 256), 256, 0, stream>>>(W2ih, 1024, 1024, W2hh, 1024,
                                               4, 1024, 16, 64, W2p);
    pack_sm4<<<1536, 256, 0, stream>>>(enc_img_W, enc_mean_W, att_Ua, att_Wa,
                                       WiP, WmP, WuaP, WaP);
    pack_wae<<<1024, 256, 0, stream>>>(att_Wa, WaE);
    pack_cm<<<dim3(250, 32), 256, 0, stream>>>(embW, WvP);
    pack_emb<<<960, 256, 0, stream>>>(Wemb, captions, embP);

    enc_gemm<64><<<dim3(16, 40), 256, 0, stream>>>(afP, WiP, enc_img_b, vf, vfP);
    p3_gemm<<<16, 256, 0, stream>>>(fmP, WmP, enc_mean_b, x1p0, h2hist);
    enc_gemm<32><<<dim3(16, 40), 256, 0, stream>>>(vfP, WuaP, att_ba, imgp, nullptr);
    gemb_gemm<<<1920, 256, 0, stream>>>(embP, W1p, Gemb);
    hwa_gemm<<<16, 512, 0, stream>>>(h2hist, WaP, hw);   // s=0 only

    for (int s = 0; s < kNS; ++s) {
        us* x1c = (s & 1) ? x1p1 : x1p0;
        us* x1n = (s & 1) ? x1p0 : x1p1;
        us* x2c = (s & 1) ? x2p1 : x2p0;
        us* x2n = (s & 1) ? x2p0 : x2p1;
        attn_fused<<<64, 256, 0, stream>>>(
            (s == 0) ? hw : nullptr, hwPart, imgp, att_w, vf, video_mask, x1c);
        gates_cell<64, 96, 32><<<64, 1024, 0, stream>>>(
            x1c, W1p, bsum1, Gemb + (size_t)s * 64 * 4096, c1,
            x1n, 1024, x2c, 0);
        gates2_cell<<<64, 1024, 0, stream>>>(
            x2c, W2p, bsum2, c2,
            x2n, 1024, h2hist + (size_t)(s + 1) * 65536, 0,
            (s < kNS - 1) ? hwPart : nullptr, WaE);
    }
    logits_sb<<<2560, 256, 0, stream>>>(h2hist, WvP, embb, captions, psumP, tlogs);
    final_loss<<<kNS, 256, 0, stream>>>(psumP, tlogs, msum, (float*)d_out);
}

// Round 13
// 1883.054 us; speedup vs baseline: 1.0967x; 1.0967x over previous
//
#include <hip/hip_runtime.h>
#include <stdint.h>

constexpr int kB   = 64;
constexpr int kTV  = 40;
constexpr int kF   = 2048;
constexpr int kH   = 1024;
constexpr int kV   = 32000;
constexpr int kNS  = 30;
constexpr int kCAP = 31;

typedef __attribute__((ext_vector_type(8))) short bf16x8;
typedef __attribute__((ext_vector_type(4))) float f32x4;
typedef unsigned short us;

__device__ __forceinline__ float sigm(float x) { return 1.f / (1.f + __expf(-x)); }
__device__ __forceinline__ float tanh_fast(float x) {
    float e = __expf(2.f * x);
    return 1.f - 2.f / (e + 1.f);
}
__device__ __forceinline__ us f2bf(float x) {
    unsigned u = __float_as_uint(x);
    return (us)((u + 0x7fffu + ((u >> 16) & 1u)) >> 16);
}
__device__ __forceinline__ float bf2f(us u) {
    return __uint_as_float((unsigned)u << 16);
}

__device__ __forceinline__ void gl16(const us* g, us* lds) {
    __builtin_amdgcn_global_load_lds(
        (const __attribute__((address_space(1))) unsigned int*)(g),
        (__attribute__((address_space(3))) unsigned int*)(lds), 16, 0, 0);
}

template <int N>
__device__ __forceinline__ void waitv() {
    asm volatile("s_waitcnt vmcnt(%0)" :: "n"(N) : "memory");
}
__device__ __forceinline__ void barrier_raw() {
    __builtin_amdgcn_s_barrier();
    asm volatile("" ::: "memory");
}

// A-packed layout: [kt][ms][lane][j]; (row,col): ms=row>>4,
// lane=(row&15)+16*((kc>>2)&3), j=(kc&3)+4*(kc>>4), kc=col&31, kt=col>>5.
__device__ __forceinline__ void store_packedA(us* base, int row, int col, us v) {
    int kt = col >> 5, kc = col & 31, ms = row >> 4;
    int l = (row & 15) + (((kc >> 2) & 3) << 4);
    int j = (kc & 3) + ((kc >> 4) << 2);
    base[((((size_t)kt * 4 + ms) * 64 + l) << 3) + j] = v;
}

// ---------------- single-barrier 3-slot depth-2 MFMA K-loop ----------------
// stage(t+2) targets slot (t-1)%3 whose readers finished before this
// iteration's barrier (ds_reads complete before their MFMAs -> before barrier).
template <int NSPW, int KT>
__device__ __forceinline__ void mfma_kloop(
    const us* __restrict__ Ap, const us* __restrict__ Bp,
    us* Asm, us* Bsm, int w, int l, f32x4 acc[4][NSPW])
{
    constexpr int BSTEP = 2048 * NSPW;
    constexpr int LPT = 1 + NSPW;
    auto stage = [&](int t, int slot) {
        gl16(Ap + (size_t)t * 2048 + w * 512 + l * 8, Asm + slot * 2048 + w * 512);
#pragma unroll
        for (int i = 0; i < NSPW; ++i)
            gl16(Bp + (size_t)t * BSTEP + (w * NSPW + i) * 512 + l * 8,
                 Bsm + slot * BSTEP + (w * NSPW + i) * 512);
    };
    stage(0, 0);
    if (1 < KT) stage(1, 1);
#pragma unroll 1
    for (int t = 0; t < KT; ++t) {
        int slot = t % 3;
        if (t + 1 < KT) waitv<LPT>();
        else waitv<0>();
        barrier_raw();
        if (t + 2 < KT) stage(t + 2, (t + 2) % 3);
        bf16x8 bfr[NSPW], afr[4];
#pragma unroll
        for (int i = 0; i < NSPW; ++i)
            bfr[i] = *(const bf16x8*)(Bsm + slot * BSTEP + ((w * NSPW + i) * 64 + l) * 8);
#pragma unroll
        for (int ms = 0; ms < 4; ++ms)
            afr[ms] = *(const bf16x8*)(Asm + slot * 2048 + (ms * 64 + l) * 8);
#pragma unroll
        for (int ms = 0; ms < 4; ++ms)
#pragma unroll
            for (int i = 0; i < NSPW; ++i)
                acc[ms][i] = __builtin_amdgcn_mfma_f32_16x16x32_bf16(
                    afr[ms], bfr[i], acc[ms][i], 0, 0, 0);
        __builtin_amdgcn_sched_barrier(0);
    }
}

// ---------------- prep: feat mean + bias sums + mask sums ----------------
__global__ __launch_bounds__(256) void prep_mean(
    const float* __restrict__ af, float* __restrict__ fm,
    const float* __restrict__ bih1, const float* __restrict__ bhh1,
    const float* __restrict__ bih2, const float* __restrict__ bhh2,
    const float* __restrict__ capmask,
    float* __restrict__ bsum1, float* __restrict__ bsum2, float* __restrict__ msum)
{
    int tid = threadIdx.x;
    if (blockIdx.x < 64) {
        int b = blockIdx.x;
        const float* base = af + (size_t)b * kTV * kF;
        float a[8] = {};
        for (int t = 0; t < kTV; ++t) {
            const float* rp = base + (size_t)t * kF + tid * 8;
            float4 v0 = *(const float4*)rp;
            float4 v1 = *(const float4*)(rp + 4);
            a[0] += v0.x; a[1] += v0.y; a[2] += v0.z; a[3] += v0.w;
            a[4] += v1.x; a[5] += v1.y; a[6] += v1.z; a[7] += v1.w;
        }
        float* op = fm + (size_t)b * kF + tid * 8;
#pragma unroll
        for (int j = 0; j < 8; ++j) op[j] = a[j] * (1.f / kTV);
    } else {
        int g = (blockIdx.x - 64) * 256 + tid;
        if (g < 4096) bsum1[g] = bih1[g] + bhh1[g];
        else if (g < 8192) { int j = g - 4096; bsum2[j] = bih2[j] + bhh2[j]; }
        else if (g < 8192 + kNS) {
            int t = g - 8192;
            float s = 0.f;
            for (int b = 0; b < kB; ++b) s += capmask[b * kCAP + t + 1];
            msum[t] = s;
        }
    }
}

// ---------------- packing: row-major source(s) -> fragment tiles ----------------
__global__ __launch_bounds__(256) void pack_rm(
    const float* __restrict__ p0, int ld0, int ksplit,
    const float* __restrict__ p1, int ld1,
    int NGRP, int GS, int HS, int KT,
    us* __restrict__ out)
{
    __shared__ us tile[16][136];
    int kb = blockIdx.x * 128;
    int grp = blockIdx.y;
    int row0 = (grp % NGRP) * GS + (grp / NGRP) * HS;
    int tid = threadIdx.x;
    int r = tid >> 5, c4 = (tid & 31) * 4;
#pragma unroll
    for (int pass = 0; pass < 2; ++pass) {
        int rr = r + pass * 8;
        int row = row0 + rr;
        int k = kb + c4;
        float4 v;
        if (k < ksplit) v = *(const float4*)(p0 + (size_t)row * ld0 + k);
        else            v = *(const float4*)(p1 + (size_t)row * ld1 + (k - ksplit));
        ushort4 o; o.x = f2bf(v.x); o.y = f2bf(v.y); o.z = f2bf(v.z); o.w = f2bf(v.w);
        *(ushort4*)&tile[rr][c4] = o;
    }
    __syncthreads();
    int ktl = tid >> 6, l = tid & 63, ul = l & 15, q = (l >> 4) & 3;
    __align__(16) us o2[8];
#pragma unroll
    for (int j = 0; j < 8; ++j) {
        int kc = (j & 3) + q * 4 + ((j >> 2) << 4);
        o2[j] = tile[ul][ktl * 32 + kc];
    }
    int kt = (kb >> 5) + ktl;
    size_t base = (((size_t)(grp / NGRP) * KT + kt) * NGRP + (grp % NGRP)) * 512;
    *(uint4*)(out + base + (size_t)l * 8) = *(const uint4*)o2;
}

// vocab [K][32000] -> B tiles S=8
__global__ __launch_bounds__(256) void pack_cm(const float* __restrict__ W,
                                               us* __restrict__ out)
{
    __shared__ us tile[32][136];
    int n0 = blockIdx.x * 128, k0 = blockIdx.y * 32;
    int tid = threadIdx.x;
    int r = tid >> 5, c4 = (tid & 31) * 4;
#pragma unroll
    for (int pass = 0; pass < 4; ++pass) {
        int rr = r + pass * 8;
        float4 v = *(const float4*)(W + (size_t)(k0 + rr) * kV + n0 + c4);
        ushort4 o; o.x = f2bf(v.x); o.y = f2bf(v.y); o.z = f2bf(v.z); o.w = f2bf(v.w);
        *(ushort4*)&tile[rr][c4] = o;
    }
    __syncthreads();
    int ns = tid >> 5, lp = (tid & 31) * 2;
    size_t base = (((size_t)blockIdx.x * 32 + blockIdx.y) * 8 + ns) * 512;
    __align__(16) us o2[16];
#pragma unroll
    for (int li = 0; li < 2; ++li) {
        int l = lp + li, ul = l & 15, q = (l >> 4) & 3;
#pragma unroll
        for (int j = 0; j < 8; ++j) {
            int kc = (j & 3) + q * 4 + ((j >> 2) << 4);
            o2[li * 8 + j] = tile[kc][ns * 16 + ul];
        }
    }
    *(uint4*)(out + base + lp * 8) = *(const uint4*)&o2[0];
    *(uint4*)(out + base + lp * 8 + 8) = *(const uint4*)&o2[8];
}

// 4 small [K][1024] weights -> B tiles S=4, coalesced LDS-staged
__global__ __launch_bounds__(256) void pack_sm4(
    const float* __restrict__ Wi, const float* __restrict__ Wm,
    const float* __restrict__ Wua, const float* __restrict__ Wa,
    us* __restrict__ oi, us* __restrict__ om,
    us* __restrict__ oua, us* __restrict__ oa)
{
    int bid = blockIdx.x;
    const float* W; us* out; int KT, rel;
    if (bid < 512)       { W = Wi;  out = oi;  KT = 64; rel = bid; }
    else if (bid < 1024) { W = Wm;  out = om;  KT = 64; rel = bid - 512; }
    else if (bid < 1280) { W = Wua; out = oua; KT = 32; rel = bid - 1024; }
    else                 { W = Wa;  out = oa;  KT = 32; rel = bid - 1280; }
    int bx = rel & 7, by = rel >> 3;
    __shared__ us tile[32][136];
    int n0 = bx * 128, k0 = by * 32;
    int tid = threadIdx.x;
    int r = tid >> 5, c4 = (tid & 31) * 4;
#pragma unroll
    for (int pass = 0; pass < 4; ++pass) {
        int rr = r + pass * 8;
        float4 v = *(const float4*)(W + (size_t)(k0 + rr) * 1024 + n0 + c4);
        ushort4 o; o.x = f2bf(v.x); o.y = f2bf(v.y); o.z = f2bf(v.z); o.w = f2bf(v.w);
        *(ushort4*)&tile[rr][c4] = o;
    }
    __syncthreads();
    int ns = tid >> 5, lp = (tid & 31) * 2;
    int nb64 = bx * 2 + (ns >> 2), ns4 = ns & 3;
    size_t base = (((size_t)nb64 * KT + by) * 4 + ns4) * 512;
    __align__(16) us o2[16];
#pragma unroll
    for (int li = 0; li < 2; ++li) {
        int l = lp + li, ul = l & 15, q = (l >> 4) & 3;
#pragma unroll
        for (int j = 0; j < 8; ++j) {
            int kc = (j & 3) + q * 4 + ((j >> 2) << 4);
            o2[li * 8 + j] = tile[kc][ns * 16 + ul];
        }
    }
    *(uint4*)(out + base + lp * 8) = *(const uint4*)&o2[0];
    *(uint4*)(out + base + lp * 8 + 8) = *(const uint4*)&o2[8];
}

// Wa -> WaE[nb][cb][ns][64][8]: K=32 B-frags, k 0-15 = Wa rows nb*16+k, k>=16 zero
__global__ __launch_bounds__(256) void pack_wae(const float* __restrict__ Wa,
                                                us* __restrict__ WaE)
{
    int nb = blockIdx.x >> 4, cb = blockIdx.x & 15;
    int tid = threadIdx.x;
    int ns = tid >> 6, l = tid & 63;
    int ul = l & 15, q = (l >> 4) & 3;
    int col = cb * 64 + ns * 16 + ul;
    __align__(16) us o[8];
#pragma unroll
    for (int j = 0; j < 4; ++j) {
        int k = (j & 3) + q * 4;               // 0..15
        o[j] = f2bf(Wa[(size_t)(nb * 16 + k) * kH + col]);
    }
    o[4] = 0; o[5] = 0; o[6] = 0; o[7] = 0;
    size_t base = (((size_t)(nb * 16 + cb)) * 4 + ns) * 512;
    *(uint4*)(WaE + base + (size_t)l * 8) = *(const uint4*)o;
}

// per-step emb rows -> A-packed tiles: embP[s][kt32][ms4][512]
__global__ __launch_bounds__(256) void pack_emb(
    const float* __restrict__ Wemb, const int* __restrict__ captions,
    us* __restrict__ embP)
{
    __shared__ us tile[16][136];
    int rel = blockIdx.x;              // 960 = 30 s x 4 rg x 8 kb
    int s = rel / 32, rem = rel % 32;
    int rg = rem & 3, kb8 = rem >> 2;
    int tid = threadIdx.x;
    int r = tid >> 5, c4 = (tid & 31) * 4;
#pragma unroll
    for (int pass = 0; pass < 2; ++pass) {
        int rr = r + pass * 8;
        int b = rg * 16 + rr;
        int word = captions[b * kCAP + s];
        float4 v = *(const float4*)(Wemb + (size_t)word * kH + kb8 * 128 + c4);
        ushort4 o; o.x = f2bf(v.x); o.y = f2bf(v.y); o.z = f2bf(v.z); o.w = f2bf(v.w);
        *(ushort4*)&tile[rr][c4] = o;
    }
    __syncthreads();
    int ktl = tid >> 6, l = tid & 63, ul = l & 15, q = (l >> 4) & 3;
    __align__(16) us o2[8];
#pragma unroll
    for (int j = 0; j < 8; ++j) {
        int kc = (j & 3) + q * 4 + ((j >> 2) << 4);
        o2[j] = tile[ul][ktl * 32 + kc];
    }
    int kt = kb8 * 4 + ktl;
    size_t base = (((size_t)s * 32 + kt) * 4 + rg) * 512;
    *(uint4*)(embP + base + (size_t)l * 8) = *(const uint4*)o2;
}

// ---------------- encoder GEMM (LDS-staged), bf16 outF ----------------
template <int KT>
__global__ __launch_bounds__(256) void enc_gemm(
    const us* __restrict__ Ap, const us* __restrict__ Bp,
    const float* __restrict__ bias, us* __restrict__ outF,
    us* __restrict__ outP)
{
    __shared__ us Asm[3][2048];
    __shared__ us Bsm[3][2048];
    int tid = threadIdx.x, w = tid >> 6, l = tid & 63;
    int nb = blockIdx.x, mb = blockIdx.y;
    f32x4 acc[4][1] = {};
    mfma_kloop<1, KT>(Ap + (size_t)mb * KT * 2048, Bp + (size_t)nb * KT * 2048,
                      &Asm[0][0], &Bsm[0][0], w, l, acc);
    int ul = l & 15, sg = l >> 4;
    int n = nb * 64 + w * 16 + ul;
    float bv = bias[n];
#pragma unroll
    for (int ms = 0; ms < 4; ++ms)
#pragma unroll
        for (int r = 0; r < 4; ++r) {
            int rl = ms * 16 + sg * 4 + r;
            int row = mb * 64 + rl;
            float v = acc[ms][0][r] + bv;
            outF[(size_t)row * kH + n] = f2bf(v);
            if (outP) store_packedA(outP + (size_t)mb * 65536, rl, n, f2bf(v));
        }
}

// P3: feat_h -> x1p0 h1-slot (col 1024+) and h2hist[0]
__global__ __launch_bounds__(256) void p3_gemm(
    const us* __restrict__ Ap, const us* __restrict__ Bp,
    const float* __restrict__ bias, us* __restrict__ xcat1p,
    us* __restrict__ h2hist0)
{
    __shared__ us Asm[3][2048];
    __shared__ us Bsm[3][2048];
    int tid = threadIdx.x, w = tid >> 6, l = tid & 63;
    int nb = blockIdx.x;
    f32x4 acc[4][1] = {};
    mfma_kloop<1, 64>(Ap, Bp + (size_t)nb * 64 * 2048, &Asm[0][0], &Bsm[0][0], w, l, acc);
    int ul = l & 15, sg = l >> 4;
    int n = nb * 64 + w * 16 + ul;
    float bv = bias[n];
#pragma unroll
    for (int ms = 0; ms < 4; ++ms)
#pragma unroll
        for (int r = 0; r < 4; ++r) {
            int row = ms * 16 + sg * 4 + r;
            us hb = f2bf(acc[ms][0][r] + bv);
            store_packedA(xcat1p, row, 1024 + n, hb);
            store_packedA(h2hist0, row, n, hb);
        }
}

// Gemb[s] = emb(s) @ W1ih[:, 0:1024] (bf16 out, gate-interleaved cols)
__global__ __launch_bounds__(256) void gemb_gemm(
    const us* __restrict__ embP, const us* __restrict__ W1p,
    us* __restrict__ Gemb)
{
    __shared__ us Asm[3][2048];
    __shared__ us Bsm[3][2048];
    int rel = blockIdx.x;              // 1920 = 30 s x 64 nb
    int s = rel >> 6, nb = rel & 63;
    int tid = threadIdx.x, w = tid >> 6, l = tid & 63;
    f32x4 acc[4][1] = {};
    mfma_kloop<1, 32>(embP + (size_t)s * 65536, W1p + (size_t)nb * 96 * 2048,
                      &Asm[0][0], &Bsm[0][0], w, l, acc);
    int ul = l & 15, sg = l >> 4;
    int n = nb * 64 + w * 16 + ul;
#pragma unroll
    for (int ms = 0; ms < 4; ++ms)
#pragma unroll
        for (int r = 0; r < 4; ++r) {
            int row = ms * 16 + sg * 4 + r;
            Gemb[((size_t)s * 64 + row) * 4096 + n] = f2bf(acc[ms][0][r]);
        }
}

// ---------------- hwa for s=0 only: hw = h2hist[0] @ att_Wa ----------------
__global__ __launch_bounds__(512) void hwa_gemm(
    const us* __restrict__ h2p, const us* __restrict__ WaP,
    float* __restrict__ hw)
{
    __shared__ __align__(16) char smem[49152];
    float* rsum = (float*)smem;
    int tid = threadIdx.x, w = tid >> 6, l = tid & 63, nb = blockIdx.x;
    int h = w >> 2, w4 = w & 3;
    us* Asm = (us*)(smem + h * 24576);
    us* Bsm = Asm + 6144;
    f32x4 acc[4][1] = {};
    mfma_kloop<1, 16>(h2p + (size_t)h * 16 * 2048,
                      WaP + (size_t)nb * 32 * 2048 + (size_t)h * 16 * 2048,
                      Asm, Bsm, w4, l, acc);
    int ul = l & 15, sg = l >> 4;
    __syncthreads();
    if (h == 1) {
#pragma unroll
        for (int ms = 0; ms < 4; ++ms)
#pragma unroll
            for (int r = 0; r < 4; ++r)
                rsum[((w4 * 64) + ms * 16 + sg * 4 + r) * 17 + ul] = acc[ms][0][r];
    }
    __syncthreads();
    if (h == 0) {
        int n = nb * 64 + w4 * 16 + ul;
#pragma unroll
        for (int ms = 0; ms < 4; ++ms)
#pragma unroll
            for (int r = 0; r < 4; ++r) {
                int row = ms * 16 + sg * 4 + r;
                hw[(size_t)row * kH + n] =
                    acc[ms][0][r] + rsum[((w4 * 64) + row) * 17 + ul];
            }
    }
}

// ---------------- fused attention (per batch row; reduces bf16 hwPart) ----------------
__global__ __launch_bounds__(256) void attn_fused(
    const float* __restrict__ hw0, const us* __restrict__ hwP,
    const us* __restrict__ imgp, const float* __restrict__ attw,
    const us* __restrict__ vf, const float* __restrict__ vmask,
    us* __restrict__ xcat1p)
{
    __shared__ float hwv[kH];
    __shared__ float es[48];
    int b = blockIdx.x, tid = threadIdx.x;
    if (hw0) {
        for (int i = tid; i < kH; i += 256) hwv[i] = hw0[(size_t)b * kH + i];
    } else {
        int c4 = tid * 4;
        float a0 = 0.f, a1 = 0.f, a2 = 0.f, a3 = 0.f;
        for (int nb = 0; nb < 64; ++nb) {
            ushort4 v = *(const ushort4*)(hwP + ((size_t)nb * 64 + b) * 1024 + c4);
            a0 += bf2f(v.x); a1 += bf2f(v.y); a2 += bf2f(v.z); a3 += bf2f(v.w);
        }
        hwv[c4 + 0] = a0; hwv[c4 + 1] = a1; hwv[c4 + 2] = a2; hwv[c4 + 3] = a3;
    }
    __syncthreads();
    int w = tid >> 6, l = tid & 63;
    for (int t = w; t < kTV; t += 4) {
        const us* ip = imgp + ((size_t)b * kTV + t) * kH;
        float p = 0.f;
#pragma unroll
        for (int hh = 0; hh < 16; ++hh) {
            int h = hh * 64 + l;
            p += tanh_fast(hwv[h] + bf2f(ip[h])) * attw[h];
        }
        for (int off = 32; off; off >>= 1) p += __shfl_down(p, off);
        if (l == 0) es[t] = p;
    }
    __syncthreads();
    float mx = -1e30f;
    for (int t = 0; t < kTV; ++t) mx = fmaxf(mx, es[t]);
    const float* vm = vmask + b * kTV;
    float den = 0.f;
    for (int t = 0; t < kTV; ++t) den += vm[t] * __expf(es[t] - mx);
    den = den + (den == 0.f ? 1.f : 0.f) + 1e-9f;
    int h0 = tid * 4;
    float a0 = 0.f, a1 = 0.f, a2 = 0.f, a3 = 0.f;
    for (int t = 0; t < kTV; ++t) {
        float wgt = vm[t] * __expf(es[t] - mx) / den;
        ushort4 v = *(const ushort4*)(vf + ((size_t)b * kTV + t) * kH + h0);
        a0 += wgt * bf2f(v.x); a1 += wgt * bf2f(v.y);
        a2 += wgt * bf2f(v.z); a3 += wgt * bf2f(v.w);
    }
    store_packedA(xcat1p, b, h0 + 0, f2bf(a0));
    store_packedA(xcat1p, b, h0 + 1, f2bf(a1));
    store_packedA(xcat1p, b, h0 + 2, f2bf(a2));
    store_packedA(xcat1p, b, h0 + 3, f2bf(a3));
}

// ---------------- gates1: GEMM + LSTM cell (1024 thr, staged 4-way K-split) ----------------
template <int KT, int BSTR, int KOFF>
__global__ __launch_bounds__(1024) void gates_cell(
    const us* __restrict__ Ap, const us* __restrict__ Bp,
    const float* __restrict__ bsum, const us* __restrict__ gemb,
    float* __restrict__ cbuf,
    us* __restrict__ dA, int ofsA, us* __restrict__ dB, int ofsB)
{
    __shared__ __align__(16) char smem[98304];
    float* gsm = (float*)smem;
    constexpr int KQ = KT / 4;
    int tid = threadIdx.x, w16 = tid >> 6, l = tid & 63, nb = blockIdx.x;
    int g = w16 >> 2, w4 = w16 & 3;
    us* Asm = (us*)(smem + g * 24576);
    us* Bsm = Asm + 6144;
    f32x4 acc[4][1] = {};
    mfma_kloop<1, KQ>(Ap + (size_t)g * KQ * 2048,
                      Bp + (size_t)nb * BSTR * 2048 + (size_t)(KOFF + g * KQ) * 2048,
                      Asm, Bsm, w4, l, acc);
    int ul = l & 15, sg = l >> 4;
    int sl = (g & 1) * 4 + w4;
    float bv = (g == 0) ? bsum[w4 * 1024 + nb * 16 + ul] : 0.f;
    __syncthreads();
    if (g < 2) {
#pragma unroll
        for (int ms = 0; ms < 4; ++ms)
#pragma unroll
            for (int r = 0; r < 4; ++r)
                gsm[(sl * 64 + ms * 16 + sg * 4 + r) * 17 + ul] = acc[ms][0][r] + bv;
    }
    __syncthreads();
    if (g >= 2) {
#pragma unroll
        for (int ms = 0; ms < 4; ++ms)
#pragma unroll
            for (int r = 0; r < 4; ++r)
                gsm[(sl * 64 + ms * 16 + sg * 4 + r) * 17 + ul] += acc[ms][0][r];
    }
    __syncthreads();
    {
        int row = tid >> 4, uc = tid & 15, u = nb * 16 + uc;
        float ge0 = 0.f, ge1 = 0.f, ge2 = 0.f, ge3 = 0.f;
        if (gemb) {
            const us* gp = gemb + (size_t)row * 4096 + nb * 64 + uc;
            ge0 = bf2f(gp[0]); ge1 = bf2f(gp[16]);
            ge2 = bf2f(gp[32]); ge3 = bf2f(gp[48]);
        }
        float gi = gsm[((0 * 64) + row) * 17 + uc] + gsm[((4 * 64) + row) * 17 + uc] + ge0;
        float gf = gsm[((1 * 64) + row) * 17 + uc] + gsm[((5 * 64) + row) * 17 + uc] + ge1;
        float gg = gsm[((2 * 64) + row) * 17 + uc] + gsm[((6 * 64) + row) * 17 + uc] + ge2;
        float go = gsm[((3 * 64) + row) * 17 + uc] + gsm[((7 * 64) + row) * 17 + uc] + ge3;
        float c = sigm(gf) * cbuf[(size_t)row * kH + u] + sigm(gi) * tanh_fast(gg);
        cbuf[(size_t)row * kH + u] = c;
        us hb = f2bf(sigm(go) * tanh_fast(c));
        store_packedA(dA, row, ofsA + u, hb);
        store_packedA(dB, row, ofsB + u, hb);
    }
}

// ---------------- gates2: GEMM + cell + distributed-hwa partial epilogue (bf16) ----------------
__global__ __launch_bounds__(1024) void gates2_cell(
    const us* __restrict__ Ap, const us* __restrict__ Bp,
    const float* __restrict__ bsum, float* __restrict__ cbuf,
    us* __restrict__ dA, int ofsA, us* __restrict__ dB, int ofsB,
    us* __restrict__ hwPart, const us* __restrict__ WaE)
{
    __shared__ __align__(16) char smem[98304];
    float* gsm = (float*)smem;
    us* hA = (us*)(smem + 40960);
    constexpr int KQ = 16;
    int tid = threadIdx.x, w16 = tid >> 6, l = tid & 63, nb = blockIdx.x;
    int g = w16 >> 2, w4 = w16 & 3;
    us* Asm = (us*)(smem + g * 24576);
    us* Bsm = Asm + 6144;
    f32x4 acc[4][1] = {};
    mfma_kloop<1, KQ>(Ap + (size_t)g * KQ * 2048,
                      Bp + (size_t)nb * 64 * 2048 + (size_t)(g * KQ) * 2048,
                      Asm, Bsm, w4, l, acc);
    int ul = l & 15, sg = l >> 4;
    int sl = (g & 1) * 4 + w4;
    float bv = (g == 0) ? bsum[w4 * 1024 + nb * 16 + ul] : 0.f;
    __syncthreads();
    if (g < 2) {
#pragma unroll
        for (int ms = 0; ms < 4; ++ms)
#pragma unroll
            for (int r = 0; r < 4; ++r)
                gsm[(sl * 64 + ms * 16 + sg * 4 + r) * 17 + ul] = acc[ms][0][r] + bv;
    }
    __syncthreads();
    if (g >= 2) {
#pragma unroll
        for (int ms = 0; ms < 4; ++ms)
#pragma unroll
            for (int r = 0; r < 4; ++r)
                gsm[(sl * 64 + ms * 16 + sg * 4 + r) * 17 + ul] += acc[ms][0][r];
    }
    __syncthreads();
    int row = tid >> 4, uc = tid & 15, u = nb * 16 + uc;
    {
        float gi = gsm[((0 * 64) + row) * 17 + uc] + gsm[((4 * 64) + row) * 17 + uc];
        float gf = gsm[((1 * 64) + row) * 17 + uc] + gsm[((5 * 64) + row) * 17 + uc];
        float gg = gsm[((2 * 64) + row) * 17 + uc] + gsm[((6 * 64) + row) * 17 + uc];
        float go = gsm[((3 * 64) + row) * 17 + uc] + gsm[((7 * 64) + row) * 17 + uc];
        float c = sigm(gf) * cbuf[(size_t)row * kH + u] + sigm(gi) * tanh_fast(gg);
        cbuf[(size_t)row * kH + u] = c;
        us hb = f2bf(sigm(go) * tanh_fast(c));
        store_packedA(dA, row, ofsA + u, hb);
        store_packedA(dB, row, ofsB + u, hb);
        if (hwPart) {
            *(unsigned*)(hA + tid * 2) = 0;
            __syncthreads();
            int lpos = (row & 15) + (((uc >> 2) & 3) << 4);
            hA[((((row >> 4) * 64) + lpos) << 3) + (uc & 3)] = hb;
            __syncthreads();
            int cb = w16;
            f32x4 hacc[4][4] = {};
            bf16x8 afr[4];
#pragma unroll
            for (int ms = 0; ms < 4; ++ms)
                afr[ms] = *(const bf16x8*)(hA + (ms * 64 + l) * 8);
#pragma unroll
            for (int ns = 0; ns < 4; ++ns) {
                bf16x8 bfr = *(const bf16x8*)(WaE +
                    ((((size_t)(nb * 16 + cb)) * 4 + ns) << 9) + l * 8);
#pragma unroll
                for (int ms = 0; ms < 4; ++ms)
                    hacc[ms][ns] = __builtin_amdgcn_mfma_f32_16x16x32_bf16(
                        afr[ms], bfr, hacc[ms][ns], 0, 0, 0);
            }
#pragma unroll
            for (int ms = 0; ms < 4; ++ms)
#pragma unroll
                for (int ns = 0; ns < 4; ++ns)
#pragma unroll
                    for (int r = 0; r < 4; ++r) {
                        int row2 = ms * 16 + sg * 4 + r;
                        int col = cb * 64 + ns * 16 + ul;
                        hwPart[((size_t)nb * 64 + row2) * 1024 + col] =
                            f2bf(hacc[ms][ns][r]);
                    }
        }
    }
}

// ---------------- deferred logits: 3 steps/block, 3-slot single-barrier, XCD-grouped ----------------
__global__ __launch_bounds__(256) void logits_sb(
    const us* __restrict__ h2hist, const us* __restrict__ WvP,
    const float* __restrict__ embb, const int* __restrict__ captions,
    float* __restrict__ psumP, float* __restrict__ tlogs)
{
    constexpr int SBLK = 3;
    __shared__ us Asm[SBLK][3][2048];
    __shared__ us Bsm[3][4096];
    __shared__ float rsum[4][64];
    __shared__ int stgt[SBLK][64];
    int bid = blockIdx.x;
    int c = bid & 7, q = bid >> 3;
    int sgrp = q % 10, nb = c + (q / 10) * 8;
    if (nb >= 250) return;
    int s0 = sgrp * SBLK;
    int tid = threadIdx.x, w = tid >> 6, l = tid & 63, ul = l & 15, lsg = l >> 4;
    if (tid < 64)
#pragma unroll
        for (int si = 0; si < SBLK; ++si)
            stgt[si][tid] = captions[tid * kCAP + s0 + si + 1];
    const us* Ab0 = h2hist + (size_t)(s0 + 1) * 65536;
    const us* Ab1 = h2hist + (size_t)(s0 + 2) * 65536;
    const us* Ab2 = h2hist + (size_t)(s0 + 3) * 65536;
    const us* Bb  = WvP + (size_t)nb * 32 * 4096;
    auto stage = [&](int t, int slot) {
        gl16(Ab0 + (size_t)t * 2048 + w * 512 + l * 8, &Asm[0][slot][w * 512]);
        gl16(Ab1 + (size_t)t * 2048 + w * 512 + l * 8, &Asm[1][slot][w * 512]);
        gl16(Ab2 + (size_t)t * 2048 + w * 512 + l * 8, &Asm[2][slot][w * 512]);
#pragma unroll
        for (int i = 0; i < 2; ++i)
            gl16(Bb + (size_t)t * 4096 + (w * 2 + i) * 512 + l * 8,
                 &Bsm[slot][(w * 2 + i) * 512]);
    };
    f32x4 acc[SBLK][4][2] = {};
    stage(0, 0); stage(1, 1);
#pragma unroll 1
    for (int t = 0; t < 32; ++t) {
        int slot = t % 3;
        if (t + 1 < 32) waitv<5>();
        else waitv<0>();
        barrier_raw();
        if (t + 2 < 32) stage(t + 2, (t + 2) % 3);
        bf16x8 b0 = *(const bf16x8*)&Bsm[slot][((w * 2 + 0) * 64 + l) * 8];
        bf16x8 b1 = *(const bf16x8*)&Bsm[slot][((w * 2 + 1) * 64 + l) * 8];
#pragma unroll
        for (int ms = 0; ms < 4; ++ms)
#pragma unroll
            for (int si = 0; si < SBLK; ++si) {
                bf16x8 a = *(const bf16x8*)&Asm[si][slot][(ms * 64 + l) * 8];
                acc[si][ms][0] = __builtin_amdgcn_mfma_f32_16x16x32_bf16(
                    a, b0, acc[si][ms][0], 0, 0, 0);
                acc[si][ms][1] = __builtin_amdgcn_mfma_f32_16x16x32_bf16(
                    a, b1, acc[si][ms][1], 0, 0, 0);
            }
        __builtin_amdgcn_sched_barrier(0);
    }
    int n0 = nb * 128 + (2 * w + 0) * 16 + ul;
    int n1 = nb * 128 + (2 * w + 1) * 16 + ul;
    float e0 = embb[n0], e1 = embb[n1];
#pragma unroll
    for (int si = 0; si < SBLK; ++si) {
        float ls[4][4];
#pragma unroll
        for (int ms = 0; ms < 4; ++ms)
#pragma unroll
            for (int r = 0; r < 4; ++r) {
                int row = ms * 16 + lsg * 4 + r;
                float v0 = acc[si][ms][0][r] + e0, v1 = acc[si][ms][1][r] + e1;
                ls[ms][r] = __expf(v0) + __expf(v1);
                if (n0 == stgt[si][row]) tlogs[(s0 + si) * 64 + row] = v0;
                if (n1 == stgt[si][row]) tlogs[(s0 + si) * 64 + row] = v1;
            }
#pragma unroll
        for (int m = 1; m < 16; m <<= 1)
#pragma unroll
            for (int ms = 0; ms < 4; ++ms)
#pragma unroll
                for (int r = 0; r < 4; ++r)
                    ls[ms][r] += __shfl_xor(ls[ms][r], m);
        if (ul == 0)
#pragma unroll
            for (int ms = 0; ms < 4; ++ms)
#pragma unroll
                for (int r = 0; r < 4; ++r)
                    rsum[w][ms * 16 + lsg * 4 + r] = ls[ms][r];
        __syncthreads();
        if (tid < 64)
            psumP[((size_t)(s0 + si) * 250 + nb) * 64 + tid] =
                rsum[0][tid] + rsum[1][tid] + rsum[2][tid] + rsum[3][tid];
        __syncthreads();
    }
}

// ---------------- final loss over all steps ----------------
__global__ __launch_bounds__(256) void final_loss(
    const float* __restrict__ psumP, const float* __restrict__ tlogs,
    const float* __restrict__ msum, float* __restrict__ out)
{
    __shared__ float sl[16000];
    int s = blockIdx.x, tid = threadIdx.x;
    const float* src = psumP + (size_t)s * 16000;
    for (int i = tid; i < 16000; i += 256) sl[i] = src[i];
    __syncthreads();
    if (tid < 64) {
        float tot = 0.f;
        for (int i = 0; i < 250; ++i) tot += sl[i * 64 + tid];
        float logp = tlogs[s * 64 + tid] - __logf(tot);
        float term = -logp * msum[s] * (1.f / 4096.f);
        for (int off = 32; off; off >>= 1) term += __shfl_down(term, off);
        if (tid == 0) atomicAdd(out, term);
    }
}

// ---------------- host ----------------
extern "C" void kernel_launch(void* const* d_in, const int* in_sizes, int n_in,
                              void* d_out, int out_size, void* d_ws, size_t ws_size,
                              hipStream_t stream)
{
    const float* action_feat = (const float*)d_in[1];
    const float* video_mask  = (const float*)d_in[3];
    const int*   captions    = (const int*)d_in[4];
    const float* capmask     = (const float*)d_in[5];
    const float* enc_img_W   = (const float*)d_in[6];
    const float* enc_img_b   = (const float*)d_in[7];
    const float* enc_mean_W  = (const float*)d_in[8];
    const float* enc_mean_b  = (const float*)d_in[9];
    const float* att_w       = (const float*)d_in[10];
    const float* att_Wa      = (const float*)d_in[11];
    const float* att_Ua      = (const float*)d_in[12];
    const float* att_ba      = (const float*)d_in[13];
    const float* Wemb        = (const float*)d_in[14];
    const float* embW        = (const float*)d_in[15];
    const float* embb        = (const float*)d_in[16];
    const float* W1ih        = (const float*)d_in[17];
    const float* W1hh        = (const float*)d_in[18];
    const float* b1ih        = (const float*)d_in[19];
    const float* b1hh        = (const float*)d_in[20];
    const float* W2ih        = (const float*)d_in[21];
    const float* W2hh        = (const float*)d_in[22];
    const float* b2ih        = (const float*)d_in[23];
    const float* b2hh        = (const float*)d_in[24];

    char* base = (char*)d_ws;
    size_t off = 0;
    auto alloc = [&](size_t bytes) {
        char* p = base + off;
        off = (off + bytes + 255) & ~(size_t)255;
        return p;
    };
    constexpr int BIG = 0x40000000;

    us* vf       = (us*)alloc((size_t)2560 * 1024 * 2);
    us* imgp     = (us*)alloc((size_t)2560 * 1024 * 2);
    float* fm    = (float*)alloc((size_t)64 * 2048 * 4);
    float* hw    = (float*)alloc((size_t)64 * 1024 * 4);
    us* hwPart   = (us*)alloc((size_t)64 * 64 * 1024 * 2);
    float* bsum1 = (float*)alloc(4096 * 4);
    float* bsum2 = (float*)alloc(4096 * 4);
    float* msum  = (float*)alloc(32 * 4);
    float* psumP = (float*)alloc((size_t)kNS * 250 * 64 * 4);
    float* tlogs = (float*)alloc((size_t)kNS * 64 * 4);
    us* Gemb     = (us*)alloc((size_t)kNS * 64 * 4096 * 2);
    // zero-init block: x2p[2], c1, c2 contiguous
    us* x2p0 = (us*)alloc((size_t)64 * 2048 * 2);
    us* x2p1 = (us*)alloc((size_t)64 * 2048 * 2);
    float* c1    = (float*)alloc((size_t)64 * 1024 * 4);
    float* c2    = (float*)alloc((size_t)64 * 1024 * 4);
    size_t zlen  = (size_t)((char*)(c2 + 64 * 1024) - (char*)x2p0);

    us* x1p0 = (us*)alloc((size_t)64 * 2048 * 2);
    us* x1p1 = (us*)alloc((size_t)64 * 2048 * 2);
    us* h2hist = (us*)alloc((size_t)(kNS + 1) * 64 * 1024 * 2);
    us* embP = (us*)alloc((size_t)kNS * 64 * 1024 * 2);
    us* afP  = (us*)alloc((size_t)2560 * 2048 * 2);
    us* vfP  = (us*)alloc((size_t)2560 * 1024 * 2);
    us* fmP  = (us*)alloc((size_t)64 * 2048 * 2);
    us* WiP  = (us*)alloc((size_t)2048 * 1024 * 2);
    us* WmP  = (us*)alloc((size_t)2048 * 1024 * 2);
    us* WuaP = (us*)alloc((size_t)1024 * 1024 * 2);
    us* WaP  = (us*)alloc((size_t)1024 * 1024 * 2);
    us* WaE  = (us*)alloc((size_t)64 * 16 * 4 * 512 * 2);
    us* W1p  = (us*)alloc((size_t)3072 * 4096 * 2);
    us* W2p  = (us*)alloc((size_t)2048 * 4096 * 2);
    us* WvP  = (us*)alloc((size_t)1024 * 32000 * 2);
    if (off > ws_size) return;

    hipMemsetAsync(d_out, 0, 4, stream);
    hipMemsetAsync(x2p0, 0, zlen, stream);

    prep_mean<<<97, 256, 0, stream>>>(action_feat, fm, b1ih, b1hh, b2ih, b2hh,
                                      capmask, bsum1, bsum2, msum);
    pack_rm<<<dim3(16, 4), 256, 0, stream>>>(fm, 2048, BIG, nullptr, 0,
                                             4, 16, 64, 64, fmP);
    pack_rm<<<dim3(16, 160), 256, 0, stream>>>(action_feat, 2048, BIG, nullptr, 0,
                                               4, 16, 64, 64, afP);
    pack_rm<<<dim3(24, 256), 256, 0, stream>>>(W1ih, 2048, 2048, W1hh, 1024,
                                               4, 1024, 16, 96, W1p);
    pack_rm<<<dim3(16, 256), 256, 0, stream>>>(W2ih, 1024, 1024, W2hh, 1024,
                                               4, 1024, 16, 64, W2p);
    pack_sm4<<<1536, 256, 0, stream>>>(enc_img_W, enc_mean_W, att_Ua, att_Wa,
                                       WiP, WmP, WuaP, WaP);
    pack_wae<<<1024, 256, 0, stream>>>(att_Wa, WaE);
    pack_cm<<<dim3(250, 32), 256, 0, stream>>>(embW, WvP);
    pack_emb<<<960, 256, 0, stream>>>(Wemb, captions, embP);

    enc_gemm<64><<<dim3(16, 40), 256, 0, stream>>>(afP, WiP, enc_img_b, vf, vfP);
    p3_gemm<<<16, 256, 0, stream>>>(fmP, WmP, enc_mean_b, x1p0, h2hist);
    enc_gemm<32><<<dim3(16, 40), 256, 0, stream>>>(vfP, WuaP, att_ba, imgp, nullptr);
    gemb_gemm<<<1920, 256, 0, stream>>>(embP, W1p, Gemb);
    hwa_gemm<<<16, 512, 0, stream>>>(h2hist, WaP, hw);   // s=0 only

    for (int s = 0; s < kNS; ++s) {
        us* x1c = (s & 1) ? x1p1 : x1p0;
        us* x1n = (s & 1) ? x1p0 : x1p1;
        us* x2c = (s & 1) ? x2p1 : x2p0;
        us* x2n = (s & 1) ? x2p0 : x2p1;
        attn_fused<<<64, 256, 0, stream>>>(
            (s == 0) ? hw : nullptr, hwPart, imgp, att_w, vf, video_mask, x1c);
        gates_cell<64, 96, 32><<<64, 1024, 0, stream>>>(
            x1c, W1p, bsum1, Gemb + (size_t)s * 64 * 4096, c1,
            x1n, 1024, x2c, 0);
        gates2_cell<<<64, 1024, 0, stream>>>(
            x2c, W2p, bsum2, c2,
            x2n, 1024, h2hist + (size_t)(s + 1) * 65536, 0,
            (s < kNS - 1) ? hwPart : nullptr, WaE);
    }
    logits_sb<<<2560, 256, 0, stream>>>(h2hist, WvP, embb, captions, psumP, tlogs);
    final_loss<<<kNS, 256, 0, stream>>>(psumP, tlogs, msum, (float*)d_out);
}

// Round 14
// 1806.871 us; speedup vs baseline: 1.1430x; 1.0422x over previous
//
#include <hip/hip_runtime.h>
#include <stdint.h>

constexpr int kB   = 64;
constexpr int kTV  = 40;
constexpr int kF   = 2048;
constexpr int kH   = 1024;
constexpr int kV   = 32000;
constexpr int kNS  = 30;
constexpr int kCAP = 31;

typedef __attribute__((ext_vector_type(8))) short bf16x8;
typedef __attribute__((ext_vector_type(4))) float f32x4;
typedef unsigned short us;

__device__ __forceinline__ float sigm(float x) { return 1.f / (1.f + __expf(-x)); }
__device__ __forceinline__ float tanh_fast(float x) {
    float e = __expf(2.f * x);
    return 1.f - 2.f / (e + 1.f);
}
__device__ __forceinline__ us f2bf(float x) {
    unsigned u = __float_as_uint(x);
    return (us)((u + 0x7fffu + ((u >> 16) & 1u)) >> 16);
}
__device__ __forceinline__ float bf2f(us u) {
    return __uint_as_float((unsigned)u << 16);
}

__device__ __forceinline__ void gl16(const us* g, us* lds) {
    __builtin_amdgcn_global_load_lds(
        (const __attribute__((address_space(1))) unsigned int*)(g),
        (__attribute__((address_space(3))) unsigned int*)(lds), 16, 0, 0);
}

template <int N>
__device__ __forceinline__ void waitv() {
    asm volatile("s_waitcnt vmcnt(%0)" :: "n"(N) : "memory");
}
__device__ __forceinline__ void barrier_raw() {
    __builtin_amdgcn_s_barrier();
    asm volatile("" ::: "memory");
}

// A-packed layout: [kt][ms][lane][j]; (row,col): ms=row>>4,
// lane=(row&15)+16*((kc>>2)&3), j=(kc&3)+4*(kc>>4), kc=col&31, kt=col>>5.
__device__ __forceinline__ void store_packedA(us* base, int row, int col, us v) {
    int kt = col >> 5, kc = col & 31, ms = row >> 4;
    int l = (row & 15) + (((kc >> 2) & 3) << 4);
    int j = (kc & 3) + ((kc >> 4) << 2);
    base[((((size_t)kt * 4 + ms) * 64 + l) << 3) + j] = v;
}

// ---------------- single-barrier 3-slot depth-2 MFMA K-loop ----------------
template <int NSPW, int KT>
__device__ __forceinline__ void mfma_kloop(
    const us* __restrict__ Ap, const us* __restrict__ Bp,
    us* Asm, us* Bsm, int w, int l, f32x4 acc[4][NSPW])
{
    constexpr int BSTEP = 2048 * NSPW;
    constexpr int LPT = 1 + NSPW;
    auto stage = [&](int t, int slot) {
        gl16(Ap + (size_t)t * 2048 + w * 512 + l * 8, Asm + slot * 2048 + w * 512);
#pragma unroll
        for (int i = 0; i < NSPW; ++i)
            gl16(Bp + (size_t)t * BSTEP + (w * NSPW + i) * 512 + l * 8,
                 Bsm + slot * BSTEP + (w * NSPW + i) * 512);
    };
    stage(0, 0);
    if (1 < KT) stage(1, 1);
#pragma unroll 1
    for (int t = 0; t < KT; ++t) {
        int slot = t % 3;
        if (t + 1 < KT) waitv<LPT>();
        else waitv<0>();
        barrier_raw();
        if (t + 2 < KT) stage(t + 2, (t + 2) % 3);
        bf16x8 bfr[NSPW], afr[4];
#pragma unroll
        for (int i = 0; i < NSPW; ++i)
            bfr[i] = *(const bf16x8*)(Bsm + slot * BSTEP + ((w * NSPW + i) * 64 + l) * 8);
#pragma unroll
        for (int ms = 0; ms < 4; ++ms)
            afr[ms] = *(const bf16x8*)(Asm + slot * 2048 + (ms * 64 + l) * 8);
#pragma unroll
        for (int ms = 0; ms < 4; ++ms)
#pragma unroll
            for (int i = 0; i < NSPW; ++i)
                acc[ms][i] = __builtin_amdgcn_mfma_f32_16x16x32_bf16(
                    afr[ms], bfr[i], acc[ms][i], 0, 0, 0);
        __builtin_amdgcn_sched_barrier(0);
    }
}

// ---------------- prep: feat mean + bias sums + mask sums ----------------
__global__ __launch_bounds__(256) void prep_mean(
    const float* __restrict__ af, float* __restrict__ fm,
    const float* __restrict__ bih1, const float* __restrict__ bhh1,
    const float* __restrict__ bih2, const float* __restrict__ bhh2,
    const float* __restrict__ capmask,
    float* __restrict__ bsum1, float* __restrict__ bsum2, float* __restrict__ msum)
{
    int tid = threadIdx.x;
    if (blockIdx.x < 64) {
        int b = blockIdx.x;
        const float* base = af + (size_t)b * kTV * kF;
        float a[8] = {};
        for (int t = 0; t < kTV; ++t) {
            const float* rp = base + (size_t)t * kF + tid * 8;
            float4 v0 = *(const float4*)rp;
            float4 v1 = *(const float4*)(rp + 4);
            a[0] += v0.x; a[1] += v0.y; a[2] += v0.z; a[3] += v0.w;
            a[4] += v1.x; a[5] += v1.y; a[6] += v1.z; a[7] += v1.w;
        }
        float* op = fm + (size_t)b * kF + tid * 8;
#pragma unroll
        for (int j = 0; j < 8; ++j) op[j] = a[j] * (1.f / kTV);
    } else {
        int g = (blockIdx.x - 64) * 256 + tid;
        if (g < 4096) bsum1[g] = bih1[g] + bhh1[g];
        else if (g < 8192) { int j = g - 4096; bsum2[j] = bih2[j] + bhh2[j]; }
        else if (g < 8192 + kNS) {
            int t = g - 8192;
            float s = 0.f;
            for (int b = 0; b < kB; ++b) s += capmask[b * kCAP + t + 1];
            msum[t] = s;
        }
    }
}

// ---------------- packing: row-major source(s) -> fragment tiles ----------------
__global__ __launch_bounds__(256) void pack_rm(
    const float* __restrict__ p0, int ld0, int ksplit,
    const float* __restrict__ p1, int ld1,
    int NGRP, int GS, int HS, int KT,
    us* __restrict__ out)
{
    __shared__ us tile[16][136];
    int kb = blockIdx.x * 128;
    int grp = blockIdx.y;
    int row0 = (grp % NGRP) * GS + (grp / NGRP) * HS;
    int tid = threadIdx.x;
    int r = tid >> 5, c4 = (tid & 31) * 4;
#pragma unroll
    for (int pass = 0; pass < 2; ++pass) {
        int rr = r + pass * 8;
        int row = row0 + rr;
        int k = kb + c4;
        float4 v;
        if (k < ksplit) v = *(const float4*)(p0 + (size_t)row * ld0 + k);
        else            v = *(const float4*)(p1 + (size_t)row * ld1 + (k - ksplit));
        ushort4 o; o.x = f2bf(v.x); o.y = f2bf(v.y); o.z = f2bf(v.z); o.w = f2bf(v.w);
        *(ushort4*)&tile[rr][c4] = o;
    }
    __syncthreads();
    int ktl = tid >> 6, l = tid & 63, ul = l & 15, q = (l >> 4) & 3;
    __align__(16) us o2[8];
#pragma unroll
    for (int j = 0; j < 8; ++j) {
        int kc = (j & 3) + q * 4 + ((j >> 2) << 4);
        o2[j] = tile[ul][ktl * 32 + kc];
    }
    int kt = (kb >> 5) + ktl;
    size_t base = (((size_t)(grp / NGRP) * KT + kt) * NGRP + (grp % NGRP)) * 512;
    *(uint4*)(out + base + (size_t)l * 8) = *(const uint4*)o2;
}

// vocab [K][32000] -> B tiles S=8
__global__ __launch_bounds__(256) void pack_cm(const float* __restrict__ W,
                                               us* __restrict__ out)
{
    __shared__ us tile[32][136];
    int n0 = blockIdx.x * 128, k0 = blockIdx.y * 32;
    int tid = threadIdx.x;
    int r = tid >> 5, c4 = (tid & 31) * 4;
#pragma unroll
    for (int pass = 0; pass < 4; ++pass) {
        int rr = r + pass * 8;
        float4 v = *(const float4*)(W + (size_t)(k0 + rr) * kV + n0 + c4);
        ushort4 o; o.x = f2bf(v.x); o.y = f2bf(v.y); o.z = f2bf(v.z); o.w = f2bf(v.w);
        *(ushort4*)&tile[rr][c4] = o;
    }
    __syncthreads();
    int ns = tid >> 5, lp = (tid & 31) * 2;
    size_t base = (((size_t)blockIdx.x * 32 + blockIdx.y) * 8 + ns) * 512;
    __align__(16) us o2[16];
#pragma unroll
    for (int li = 0; li < 2; ++li) {
        int l = lp + li, ul = l & 15, q = (l >> 4) & 3;
#pragma unroll
        for (int j = 0; j < 8; ++j) {
            int kc = (j & 3) + q * 4 + ((j >> 2) << 4);
            o2[li * 8 + j] = tile[kc][ns * 16 + ul];
        }
    }
    *(uint4*)(out + base + lp * 8) = *(const uint4*)&o2[0];
    *(uint4*)(out + base + lp * 8 + 8) = *(const uint4*)&o2[8];
}

// 4 small [K][1024] weights -> B tiles S=4, coalesced LDS-staged
__global__ __launch_bounds__(256) void pack_sm4(
    const float* __restrict__ Wi, const float* __restrict__ Wm,
    const float* __restrict__ Wua, const float* __restrict__ Wa,
    us* __restrict__ oi, us* __restrict__ om,
    us* __restrict__ oua, us* __restrict__ oa)
{
    int bid = blockIdx.x;
    const float* W; us* out; int KT, rel;
    if (bid < 512)       { W = Wi;  out = oi;  KT = 64; rel = bid; }
    else if (bid < 1024) { W = Wm;  out = om;  KT = 64; rel = bid - 512; }
    else if (bid < 1280) { W = Wua; out = oua; KT = 32; rel = bid - 1024; }
    else                 { W = Wa;  out = oa;  KT = 32; rel = bid - 1280; }
    int bx = rel & 7, by = rel >> 3;
    __shared__ us tile[32][136];
    int n0 = bx * 128, k0 = by * 32;
    int tid = threadIdx.x;
    int r = tid >> 5, c4 = (tid & 31) * 4;
#pragma unroll
    for (int pass = 0; pass < 4; ++pass) {
        int rr = r + pass * 8;
        float4 v = *(const float4*)(W + (size_t)(k0 + rr) * 1024 + n0 + c4);
        ushort4 o; o.x = f2bf(v.x); o.y = f2bf(v.y); o.z = f2bf(v.z); o.w = f2bf(v.w);
        *(ushort4*)&tile[rr][c4] = o;
    }
    __syncthreads();
    int ns = tid >> 5, lp = (tid & 31) * 2;
    int nb64 = bx * 2 + (ns >> 2), ns4 = ns & 3;
    size_t base = (((size_t)nb64 * KT + by) * 4 + ns4) * 512;
    __align__(16) us o2[16];
#pragma unroll
    for (int li = 0; li < 2; ++li) {
        int l = lp + li, ul = l & 15, q = (l >> 4) & 3;
#pragma unroll
        for (int j = 0; j < 8; ++j) {
            int kc = (j & 3) + q * 4 + ((j >> 2) << 4);
            o2[li * 8 + j] = tile[kc][ns * 16 + ul];
        }
    }
    *(uint4*)(out + base + lp * 8) = *(const uint4*)&o2[0];
    *(uint4*)(out + base + lp * 8 + 8) = *(const uint4*)&o2[8];
}

// Wa -> WaE[nb][cb][ns][64][8]: K=32 B-frags, k 0-15 = Wa rows nb*16+k, k>=16 zero
__global__ __launch_bounds__(256) void pack_wae(const float* __restrict__ Wa,
                                                us* __restrict__ WaE)
{
    int nb = blockIdx.x >> 4, cb = blockIdx.x & 15;
    int tid = threadIdx.x;
    int ns = tid >> 6, l = tid & 63;
    int ul = l & 15, q = (l >> 4) & 3;
    int col = cb * 64 + ns * 16 + ul;
    __align__(16) us o[8];
#pragma unroll
    for (int j = 0; j < 4; ++j) {
        int k = (j & 3) + q * 4;               // 0..15
        o[j] = f2bf(Wa[(size_t)(nb * 16 + k) * kH + col]);
    }
    o[4] = 0; o[5] = 0; o[6] = 0; o[7] = 0;
    size_t base = (((size_t)(nb * 16 + cb)) * 4 + ns) * 512;
    *(uint4*)(WaE + base + (size_t)l * 8) = *(const uint4*)o;
}

// per-step emb rows -> A-packed tiles: embP[s][kt32][ms4][512]
__global__ __launch_bounds__(256) void pack_emb(
    const float* __restrict__ Wemb, const int* __restrict__ captions,
    us* __restrict__ embP)
{
    __shared__ us tile[16][136];
    int rel = blockIdx.x;              // 960 = 30 s x 4 rg x 8 kb
    int s = rel / 32, rem = rel % 32;
    int rg = rem & 3, kb8 = rem >> 2;
    int tid = threadIdx.x;
    int r = tid >> 5, c4 = (tid & 31) * 4;
#pragma unroll
    for (int pass = 0; pass < 2; ++pass) {
        int rr = r + pass * 8;
        int b = rg * 16 + rr;
        int word = captions[b * kCAP + s];
        float4 v = *(const float4*)(Wemb + (size_t)word * kH + kb8 * 128 + c4);
        ushort4 o; o.x = f2bf(v.x); o.y = f2bf(v.y); o.z = f2bf(v.z); o.w = f2bf(v.w);
        *(ushort4*)&tile[rr][c4] = o;
    }
    __syncthreads();
    int ktl = tid >> 6, l = tid & 63, ul = l & 15, q = (l >> 4) & 3;
    __align__(16) us o2[8];
#pragma unroll
    for (int j = 0; j < 8; ++j) {
        int kc = (j & 3) + q * 4 + ((j >> 2) << 4);
        o2[j] = tile[ul][ktl * 32 + kc];
    }
    int kt = kb8 * 4 + ktl;
    size_t base = (((size_t)s * 32 + kt) * 4 + rg) * 512;
    *(uint4*)(embP + base + (size_t)l * 8) = *(const uint4*)o2;
}

// ---------------- encoder GEMM (LDS-staged), bf16 outF ----------------
template <int KT>
__global__ __launch_bounds__(256) void enc_gemm(
    const us* __restrict__ Ap, const us* __restrict__ Bp,
    const float* __restrict__ bias, us* __restrict__ outF,
    us* __restrict__ outP)
{
    __shared__ us Asm[3][2048];
    __shared__ us Bsm[3][2048];
    int tid = threadIdx.x, w = tid >> 6, l = tid & 63;
    int nb = blockIdx.x, mb = blockIdx.y;
    f32x4 acc[4][1] = {};
    mfma_kloop<1, KT>(Ap + (size_t)mb * KT * 2048, Bp + (size_t)nb * KT * 2048,
                      &Asm[0][0], &Bsm[0][0], w, l, acc);
    int ul = l & 15, sg = l >> 4;
    int n = nb * 64 + w * 16 + ul;
    float bv = bias[n];
#pragma unroll
    for (int ms = 0; ms < 4; ++ms)
#pragma unroll
        for (int r = 0; r < 4; ++r) {
            int rl = ms * 16 + sg * 4 + r;
            int row = mb * 64 + rl;
            float v = acc[ms][0][r] + bv;
            outF[(size_t)row * kH + n] = f2bf(v);
            if (outP) store_packedA(outP + (size_t)mb * 65536, rl, n, f2bf(v));
        }
}

// P3: feat_h -> x1p0 h1-slot (col 1024+) and h2hist[0]
__global__ __launch_bounds__(256) void p3_gemm(
    const us* __restrict__ Ap, const us* __restrict__ Bp,
    const float* __restrict__ bias, us* __restrict__ xcat1p,
    us* __restrict__ h2hist0)
{
    __shared__ us Asm[3][2048];
    __shared__ us Bsm[3][2048];
    int tid = threadIdx.x, w = tid >> 6, l = tid & 63;
    int nb = blockIdx.x;
    f32x4 acc[4][1] = {};
    mfma_kloop<1, 64>(Ap, Bp + (size_t)nb * 64 * 2048, &Asm[0][0], &Bsm[0][0], w, l, acc);
    int ul = l & 15, sg = l >> 4;
    int n = nb * 64 + w * 16 + ul;
    float bv = bias[n];
#pragma unroll
    for (int ms = 0; ms < 4; ++ms)
#pragma unroll
        for (int r = 0; r < 4; ++r) {
            int row = ms * 16 + sg * 4 + r;
            us hb = f2bf(acc[ms][0][r] + bv);
            store_packedA(xcat1p, row, 1024 + n, hb);
            store_packedA(h2hist0, row, n, hb);
        }
}

// Gemb[s] = emb(s) @ W1ih[:, 0:1024] (bf16 out, gate-interleaved cols)
__global__ __launch_bounds__(256) void gemb_gemm(
    const us* __restrict__ embP, const us* __restrict__ W1p,
    us* __restrict__ Gemb)
{
    __shared__ us Asm[3][2048];
    __shared__ us Bsm[3][2048];
    int rel = blockIdx.x;              // 1920 = 30 s x 64 nb
    int s = rel >> 6, nb = rel & 63;
    int tid = threadIdx.x, w = tid >> 6, l = tid & 63;
    f32x4 acc[4][1] = {};
    mfma_kloop<1, 32>(embP + (size_t)s * 65536, W1p + (size_t)nb * 96 * 2048,
                      &Asm[0][0], &Bsm[0][0], w, l, acc);
    int ul = l & 15, sg = l >> 4;
    int n = nb * 64 + w * 16 + ul;
#pragma unroll
    for (int ms = 0; ms < 4; ++ms)
#pragma unroll
        for (int r = 0; r < 4; ++r) {
            int row = ms * 16 + sg * 4 + r;
            Gemb[((size_t)s * 64 + row) * 4096 + n] = f2bf(acc[ms][0][r]);
        }
}

// ---------------- hwa for s=0 only: hw = h2hist[0] @ att_Wa ----------------
__global__ __launch_bounds__(512) void hwa_gemm(
    const us* __restrict__ h2p, const us* __restrict__ WaP,
    float* __restrict__ hw)
{
    __shared__ __align__(16) char smem[49152];
    float* rsum = (float*)smem;
    int tid = threadIdx.x, w = tid >> 6, l = tid & 63, nb = blockIdx.x;
    int h = w >> 2, w4 = w & 3;
    us* Asm = (us*)(smem + h * 24576);
    us* Bsm = Asm + 6144;
    f32x4 acc[4][1] = {};
    mfma_kloop<1, 16>(h2p + (size_t)h * 16 * 2048,
                      WaP + (size_t)nb * 32 * 2048 + (size_t)h * 16 * 2048,
                      Asm, Bsm, w4, l, acc);
    int ul = l & 15, sg = l >> 4;
    __syncthreads();
    if (h == 1) {
#pragma unroll
        for (int ms = 0; ms < 4; ++ms)
#pragma unroll
            for (int r = 0; r < 4; ++r)
                rsum[((w4 * 64) + ms * 16 + sg * 4 + r) * 17 + ul] = acc[ms][0][r];
    }
    __syncthreads();
    if (h == 0) {
        int n = nb * 64 + w4 * 16 + ul;
#pragma unroll
        for (int ms = 0; ms < 4; ++ms)
#pragma unroll
            for (int r = 0; r < 4; ++r) {
                int row = ms * 16 + sg * 4 + r;
                hw[(size_t)row * kH + n] =
                    acc[ms][0][r] + rsum[((w4 * 64) + row) * 17 + ul];
            }
    }
}

// ---------------- fused attention + appended logits chunk ----------------
__global__ __launch_bounds__(256) void attn_logits(
    const float* __restrict__ hw0, const us* __restrict__ hwP,
    const us* __restrict__ imgp, const float* __restrict__ attw,
    const us* __restrict__ vf, const float* __restrict__ vmask,
    us* __restrict__ xcat1p,
    const us* __restrict__ h2hist, const us* __restrict__ WvP,
    const float* __restrict__ embb, const int* __restrict__ captions,
    float* __restrict__ psumP, float* __restrict__ tlogs, int lgStart)
{
    __shared__ __align__(16) char smem[63488];
    int tid = threadIdx.x, w = tid >> 6, l = tid & 63, ul = l & 15, lsg = l >> 4;
    if (blockIdx.x >= 64) {
        us* Asm = (us*)smem;                      // [3 si][3 slot][2048]
        us* Bsm = (us*)(smem + 36864);            // [3][4096]
        float* rsum = (float*)(smem + 61440);     // [4][64]
        int* stgt = (int*)(smem + 62464);         // [3][64]
        int lb = lgStart + (int)blockIdx.x - 64;
        int g = lb / 250, nb = lb % 250;
        int s0 = g * 3;
        if (tid < 64)
#pragma unroll
            for (int si = 0; si < 3; ++si)
                stgt[si * 64 + tid] = captions[tid * kCAP + s0 + si + 1];
        const us* Ab0 = h2hist + (size_t)(s0 + 1) * 65536;
        const us* Ab1 = h2hist + (size_t)(s0 + 2) * 65536;
        const us* Ab2 = h2hist + (size_t)(s0 + 3) * 65536;
        const us* Bb  = WvP + (size_t)nb * 32 * 4096;
        auto stage = [&](int t, int slot) {
            gl16(Ab0 + (size_t)t * 2048 + w * 512 + l * 8,
                 Asm + (0 * 3 + slot) * 2048 + w * 512);
            gl16(Ab1 + (size_t)t * 2048 + w * 512 + l * 8,
                 Asm + (1 * 3 + slot) * 2048 + w * 512);
            gl16(Ab2 + (size_t)t * 2048 + w * 512 + l * 8,
                 Asm + (2 * 3 + slot) * 2048 + w * 512);
#pragma unroll
            for (int i = 0; i < 2; ++i)
                gl16(Bb + (size_t)t * 4096 + (w * 2 + i) * 512 + l * 8,
                     Bsm + slot * 4096 + (w * 2 + i) * 512);
        };
        f32x4 acc[3][4][2] = {};
        stage(0, 0); stage(1, 1);
#pragma unroll 1
        for (int t = 0; t < 32; ++t) {
            int slot = t % 3;
            if (t + 1 < 32) waitv<5>();
            else waitv<0>();
            barrier_raw();
            if (t + 2 < 32) stage(t + 2, (t + 2) % 3);
            bf16x8 b0 = *(const bf16x8*)(Bsm + slot * 4096 + ((w * 2 + 0) * 64 + l) * 8);
            bf16x8 b1 = *(const bf16x8*)(Bsm + slot * 4096 + ((w * 2 + 1) * 64 + l) * 8);
#pragma unroll
            for (int ms = 0; ms < 4; ++ms)
#pragma unroll
                for (int si = 0; si < 3; ++si) {
                    bf16x8 a = *(const bf16x8*)(Asm + (si * 3 + slot) * 2048 +
                                                (ms * 64 + l) * 8);
                    acc[si][ms][0] = __builtin_amdgcn_mfma_f32_16x16x32_bf16(
                        a, b0, acc[si][ms][0], 0, 0, 0);
                    acc[si][ms][1] = __builtin_amdgcn_mfma_f32_16x16x32_bf16(
                        a, b1, acc[si][ms][1], 0, 0, 0);
                }
            __builtin_amdgcn_sched_barrier(0);
        }
        int n0 = nb * 128 + (2 * w + 0) * 16 + ul;
        int n1 = nb * 128 + (2 * w + 1) * 16 + ul;
        float e0 = embb[n0], e1 = embb[n1];
#pragma unroll
        for (int si = 0; si < 3; ++si) {
            float ls[4][4];
#pragma unroll
            for (int ms = 0; ms < 4; ++ms)
#pragma unroll
                for (int r = 0; r < 4; ++r) {
                    int row = ms * 16 + lsg * 4 + r;
                    float v0 = acc[si][ms][0][r] + e0, v1 = acc[si][ms][1][r] + e1;
                    ls[ms][r] = __expf(v0) + __expf(v1);
                    if (n0 == stgt[si * 64 + row]) tlogs[(s0 + si) * 64 + row] = v0;
                    if (n1 == stgt[si * 64 + row]) tlogs[(s0 + si) * 64 + row] = v1;
                }
#pragma unroll
            for (int m = 1; m < 16; m <<= 1)
#pragma unroll
                for (int ms = 0; ms < 4; ++ms)
#pragma unroll
                    for (int r = 0; r < 4; ++r)
                        ls[ms][r] += __shfl_xor(ls[ms][r], m);
            if (ul == 0)
#pragma unroll
                for (int ms = 0; ms < 4; ++ms)
#pragma unroll
                    for (int r = 0; r < 4; ++r)
                        rsum[w * 64 + ms * 16 + lsg * 4 + r] = ls[ms][r];
            __syncthreads();
            if (tid < 64)
                psumP[((size_t)(s0 + si) * 250 + nb) * 64 + tid] =
                    rsum[0 * 64 + tid] + rsum[1 * 64 + tid] +
                    rsum[2 * 64 + tid] + rsum[3 * 64 + tid];
            __syncthreads();
        }
        return;
    }
    float* hwv = (float*)smem;
    float* es = (float*)(smem + 4096);
    int b = blockIdx.x;
    if (hw0) {
        for (int i = tid; i < kH; i += 256) hwv[i] = hw0[(size_t)b * kH + i];
    } else {
        int c4 = tid * 4;
        float a0 = 0.f, a1 = 0.f, a2 = 0.f, a3 = 0.f;
        for (int nb = 0; nb < 64; ++nb) {
            ushort4 v = *(const ushort4*)(hwP + ((size_t)nb * 64 + b) * 1024 + c4);
            a0 += bf2f(v.x); a1 += bf2f(v.y); a2 += bf2f(v.z); a3 += bf2f(v.w);
        }
        hwv[c4 + 0] = a0; hwv[c4 + 1] = a1; hwv[c4 + 2] = a2; hwv[c4 + 3] = a3;
    }
    __syncthreads();
    for (int t = w; t < kTV; t += 4) {
        const us* ip = imgp + ((size_t)b * kTV + t) * kH;
        float p = 0.f;
#pragma unroll
        for (int hh = 0; hh < 16; ++hh) {
            int h = hh * 64 + l;
            p += tanh_fast(hwv[h] + bf2f(ip[h])) * attw[h];
        }
        for (int off = 32; off; off >>= 1) p += __shfl_down(p, off);
        if (l == 0) es[t] = p;
    }
    __syncthreads();
    float mx = -1e30f;
    for (int t = 0; t < kTV; ++t) mx = fmaxf(mx, es[t]);
    const float* vm = vmask + b * kTV;
    float den = 0.f;
    for (int t = 0; t < kTV; ++t) den += vm[t] * __expf(es[t] - mx);
    den = den + (den == 0.f ? 1.f : 0.f) + 1e-9f;
    int h0 = tid * 4;
    float a0 = 0.f, a1 = 0.f, a2 = 0.f, a3 = 0.f;
    for (int t = 0; t < kTV; ++t) {
        float wgt = vm[t] * __expf(es[t] - mx) / den;
        ushort4 v = *(const ushort4*)(vf + ((size_t)b * kTV + t) * kH + h0);
        a0 += wgt * bf2f(v.x); a1 += wgt * bf2f(v.y);
        a2 += wgt * bf2f(v.z); a3 += wgt * bf2f(v.w);
    }
    store_packedA(xcat1p, b, h0 + 0, f2bf(a0));
    store_packedA(xcat1p, b, h0 + 1, f2bf(a1));
    store_packedA(xcat1p, b, h0 + 2, f2bf(a2));
    store_packedA(xcat1p, b, h0 + 3, f2bf(a3));
}

// ---------------- logits tail (remaining blocks after the loop) ----------------
__global__ __launch_bounds__(256) void logits_tail(
    const us* __restrict__ h2hist, const us* __restrict__ WvP,
    const float* __restrict__ embb, const int* __restrict__ captions,
    float* __restrict__ psumP, float* __restrict__ tlogs, int lgStart)
{
    __shared__ us Asm[3][3][2048];
    __shared__ us Bsm[3][4096];
    __shared__ float rsum[4][64];
    __shared__ int stgt[3][64];
    int lb = lgStart + (int)blockIdx.x;
    int g = lb / 250, nb = lb % 250;
    int s0 = g * 3;
    int tid = threadIdx.x, w = tid >> 6, l = tid & 63, ul = l & 15, lsg = l >> 4;
    if (tid < 64)
#pragma unroll
        for (int si = 0; si < 3; ++si)
            stgt[si][tid] = captions[tid * kCAP + s0 + si + 1];
    const us* Ab0 = h2hist + (size_t)(s0 + 1) * 65536;
    const us* Ab1 = h2hist + (size_t)(s0 + 2) * 65536;
    const us* Ab2 = h2hist + (size_t)(s0 + 3) * 65536;
    const us* Bb  = WvP + (size_t)nb * 32 * 4096;
    auto stage = [&](int t, int slot) {
        gl16(Ab0 + (size_t)t * 2048 + w * 512 + l * 8, &Asm[0][slot][w * 512]);
        gl16(Ab1 + (size_t)t * 2048 + w * 512 + l * 8, &Asm[1][slot][w * 512]);
        gl16(Ab2 + (size_t)t * 2048 + w * 512 + l * 8, &Asm[2][slot][w * 512]);
#pragma unroll
        for (int i = 0; i < 2; ++i)
            gl16(Bb + (size_t)t * 4096 + (w * 2 + i) * 512 + l * 8,
                 &Bsm[slot][(w * 2 + i) * 512]);
    };
    f32x4 acc[3][4][2] = {};
    stage(0, 0); stage(1, 1);
#pragma unroll 1
    for (int t = 0; t < 32; ++t) {
        int slot = t % 3;
        if (t + 1 < 32) waitv<5>();
        else waitv<0>();
        barrier_raw();
        if (t + 2 < 32) stage(t + 2, (t + 2) % 3);
        bf16x8 b0 = *(const bf16x8*)&Bsm[slot][((w * 2 + 0) * 64 + l) * 8];
        bf16x8 b1 = *(const bf16x8*)&Bsm[slot][((w * 2 + 1) * 64 + l) * 8];
#pragma unroll
        for (int ms = 0; ms < 4; ++ms)
#pragma unroll
            for (int si = 0; si < 3; ++si) {
                bf16x8 a = *(const bf16x8*)&Asm[si][slot][(ms * 64 + l) * 8];
                acc[si][ms][0] = __builtin_amdgcn_mfma_f32_16x16x32_bf16(
                    a, b0, acc[si][ms][0], 0, 0, 0);
                acc[si][ms][1] = __builtin_amdgcn_mfma_f32_16x16x32_bf16(
                    a, b1, acc[si][ms][1], 0, 0, 0);
            }
        __builtin_amdgcn_sched_barrier(0);
    }
    int n0 = nb * 128 + (2 * w + 0) * 16 + ul;
    int n1 = nb * 128 + (2 * w + 1) * 16 + ul;
    float e0 = embb[n0], e1 = embb[n1];
#pragma unroll
    for (int si = 0; si < 3; ++si) {
        float ls[4][4];
#pragma unroll
        for (int ms = 0; ms < 4; ++ms)
#pragma unroll
            for (int r = 0; r < 4; ++r) {
                int row = ms * 16 + lsg * 4 + r;
                float v0 = acc[si][ms][0][r] + e0, v1 = acc[si][ms][1][r] + e1;
                ls[ms][r] = __expf(v0) + __expf(v1);
                if (n0 == stgt[si][row]) tlogs[(s0 + si) * 64 + row] = v0;
                if (n1 == stgt[si][row]) tlogs[(s0 + si) * 64 + row] = v1;
            }
#pragma unroll
        for (int m = 1; m < 16; m <<= 1)
#pragma unroll
            for (int ms = 0; ms < 4; ++ms)
#pragma unroll
                for (int r = 0; r < 4; ++r)
                    ls[ms][r] += __shfl_xor(ls[ms][r], m);
        if (ul == 0)
#pragma unroll
            for (int ms = 0; ms < 4; ++ms)
#pragma unroll
                for (int r = 0; r < 4; ++r)
                    rsum[w][ms * 16 + lsg * 4 + r] = ls[ms][r];
        __syncthreads();
        if (tid < 64)
            psumP[((size_t)(s0 + si) * 250 + nb) * 64 + tid] =
                rsum[0][tid] + rsum[1][tid] + rsum[2][tid] + rsum[3][tid];
        __syncthreads();
    }
}

// ---------------- gates1: GEMM + LSTM cell (1024 thr, staged 4-way K-split) ----------------
template <int KT, int BSTR, int KOFF>
__global__ __launch_bounds__(1024) void gates_cell(
    const us* __restrict__ Ap, const us* __restrict__ Bp,
    const float* __restrict__ bsum, const us* __restrict__ gemb,
    float* __restrict__ cbuf,
    us* __restrict__ dA, int ofsA, us* __restrict__ dB, int ofsB)
{
    __shared__ __align__(16) char smem[98304];
    float* gsm = (float*)smem;
    constexpr int KQ = KT / 4;
    int tid = threadIdx.x, w16 = tid >> 6, l = tid & 63, nb = blockIdx.x;
    int g = w16 >> 2, w4 = w16 & 3;
    us* Asm = (us*)(smem + g * 24576);
    us* Bsm = Asm + 6144;
    f32x4 acc[4][1] = {};
    mfma_kloop<1, KQ>(Ap + (size_t)g * KQ * 2048,
                      Bp + (size_t)nb * BSTR * 2048 + (size_t)(KOFF + g * KQ) * 2048,
                      Asm, Bsm, w4, l, acc);
    int ul = l & 15, sg = l >> 4;
    int sl = (g & 1) * 4 + w4;
    float bv = (g == 0) ? bsum[w4 * 1024 + nb * 16 + ul] : 0.f;
    __syncthreads();
    if (g < 2) {
#pragma unroll
        for (int ms = 0; ms < 4; ++ms)
#pragma unroll
            for (int r = 0; r < 4; ++r)
                gsm[(sl * 64 + ms * 16 + sg * 4 + r) * 17 + ul] = acc[ms][0][r] + bv;
    }
    __syncthreads();
    if (g >= 2) {
#pragma unroll
        for (int ms = 0; ms < 4; ++ms)
#pragma unroll
            for (int r = 0; r < 4; ++r)
                gsm[(sl * 64 + ms * 16 + sg * 4 + r) * 17 + ul] += acc[ms][0][r];
    }
    __syncthreads();
    {
        int row = tid >> 4, uc = tid & 15, u = nb * 16 + uc;
        float ge0 = 0.f, ge1 = 0.f, ge2 = 0.f, ge3 = 0.f;
        if (gemb) {
            const us* gp = gemb + (size_t)row * 4096 + nb * 64 + uc;
            ge0 = bf2f(gp[0]); ge1 = bf2f(gp[16]);
            ge2 = bf2f(gp[32]); ge3 = bf2f(gp[48]);
        }
        float gi = gsm[((0 * 64) + row) * 17 + uc] + gsm[((4 * 64) + row) * 17 + uc] + ge0;
        float gf = gsm[((1 * 64) + row) * 17 + uc] + gsm[((5 * 64) + row) * 17 + uc] + ge1;
        float gg = gsm[((2 * 64) + row) * 17 + uc] + gsm[((6 * 64) + row) * 17 + uc] + ge2;
        float go = gsm[((3 * 64) + row) * 17 + uc] + gsm[((7 * 64) + row) * 17 + uc] + ge3;
        float c = sigm(gf) * cbuf[(size_t)row * kH + u] + sigm(gi) * tanh_fast(gg);
        cbuf[(size_t)row * kH + u] = c;
        us hb = f2bf(sigm(go) * tanh_fast(c));
        store_packedA(dA, row, ofsA + u, hb);
        store_packedA(dB, row, ofsB + u, hb);
    }
}

// ---------------- gates2: GEMM + cell + distributed-hwa partial epilogue (bf16) ----------------
__global__ __launch_bounds__(1024) void gates2_cell(
    const us* __restrict__ Ap, const us* __restrict__ Bp,
    const float* __restrict__ bsum, float* __restrict__ cbuf,
    us* __restrict__ dA, int ofsA, us* __restrict__ dB, int ofsB,
    us* __restrict__ hwPart, const us* __restrict__ WaE)
{
    __shared__ __align__(16) char smem[98304];
    float* gsm = (float*)smem;
    us* hA = (us*)(smem + 40960);
    constexpr int KQ = 16;
    int tid = threadIdx.x, w16 = tid >> 6, l = tid & 63, nb = blockIdx.x;
    int g = w16 >> 2, w4 = w16 & 3;
    us* Asm = (us*)(smem + g * 24576);
    us* Bsm = Asm + 6144;
    f32x4 acc[4][1] = {};
    mfma_kloop<1, KQ>(Ap + (size_t)g * KQ * 2048,
                      Bp + (size_t)nb * 64 * 2048 + (size_t)(g * KQ) * 2048,
                      Asm, Bsm, w4, l, acc);
    int ul = l & 15, sg = l >> 4;
    int sl = (g & 1) * 4 + w4;
    float bv = (g == 0) ? bsum[w4 * 1024 + nb * 16 + ul] : 0.f;
    __syncthreads();
    if (g < 2) {
#pragma unroll
        for (int ms = 0; ms < 4; ++ms)
#pragma unroll
            for (int r = 0; r < 4; ++r)
                gsm[(sl * 64 + ms * 16 + sg * 4 + r) * 17 + ul] = acc[ms][0][r] + bv;
    }
    __syncthreads();
    if (g >= 2) {
#pragma unroll
        for (int ms = 0; ms < 4; ++ms)
#pragma unroll
            for (int r = 0; r < 4; ++r)
                gsm[(sl * 64 + ms * 16 + sg * 4 + r) * 17 + ul] += acc[ms][0][r];
    }
    __syncthreads();
    int row = tid >> 4, uc = tid & 15, u = nb * 16 + uc;
    {
        float gi = gsm[((0 * 64) + row) * 17 + uc] + gsm[((4 * 64) + row) * 17 + uc];
        float gf = gsm[((1 * 64) + row) * 17 + uc] + gsm[((5 * 64) + row) * 17 + uc];
        float gg = gsm[((2 * 64) + row) * 17 + uc] + gsm[((6 * 64) + row) * 17 + uc];
        float go = gsm[((3 * 64) + row) * 17 + uc] + gsm[((7 * 64) + row) * 17 + uc];
        float c = sigm(gf) * cbuf[(size_t)row * kH + u] + sigm(gi) * tanh_fast(gg);
        cbuf[(size_t)row * kH + u] = c;
        us hb = f2bf(sigm(go) * tanh_fast(c));
        store_packedA(dA, row, ofsA + u, hb);
        store_packedA(dB, row, ofsB + u, hb);
        if (hwPart) {
            *(unsigned*)(hA + tid * 2) = 0;
            __syncthreads();
            int lpos = (row & 15) + (((uc >> 2) & 3) << 4);
            hA[((((row >> 4) * 64) + lpos) << 3) + (uc & 3)] = hb;
            __syncthreads();
            int cb = w16;
            f32x4 hacc[4][4] = {};
            bf16x8 afr[4];
#pragma unroll
            for (int ms = 0; ms < 4; ++ms)
                afr[ms] = *(const bf16x8*)(hA + (ms * 64 + l) * 8);
#pragma unroll
            for (int ns = 0; ns < 4; ++ns) {
                bf16x8 bfr = *(const bf16x8*)(WaE +
                    ((((size_t)(nb * 16 + cb)) * 4 + ns) << 9) + l * 8);
#pragma unroll
                for (int ms = 0; ms < 4; ++ms)
                    hacc[ms][ns] = __builtin_amdgcn_mfma_f32_16x16x32_bf16(
                        afr[ms], bfr, hacc[ms][ns], 0, 0, 0);
            }
#pragma unroll
            for (int ms = 0; ms < 4; ++ms)
#pragma unroll
                for (int ns = 0; ns < 4; ++ns)
#pragma unroll
                    for (int r = 0; r < 4; ++r) {
                        int row2 = ms * 16 + sg * 4 + r;
                        int col = cb * 64 + ns * 16 + ul;
                        hwPart[((size_t)nb * 64 + row2) * 1024 + col] =
                            f2bf(hacc[ms][ns][r]);
                    }
        }
    }
}

// ---------------- final loss over all steps ----------------
__global__ __launch_bounds__(256) void final_loss(
    const float* __restrict__ psumP, const float* __restrict__ tlogs,
    const float* __restrict__ msum, float* __restrict__ out)
{
    __shared__ float sl[16000];
    int s = blockIdx.x, tid = threadIdx.x;
    const float* src = psumP + (size_t)s * 16000;
    for (int i = tid; i < 16000; i += 256) sl[i] = src[i];
    __syncthreads();
    if (tid < 64) {
        float tot = 0.f;
        for (int i = 0; i < 250; ++i) tot += sl[i * 64 + tid];
        float logp = tlogs[s * 64 + tid] - __logf(tot);
        float term = -logp * msum[s] * (1.f / 4096.f);
        for (int off = 32; off; off >>= 1) term += __shfl_down(term, off);
        if (tid == 0) atomicAdd(out, term);
    }
}

// ---------------- host ----------------
extern "C" void kernel_launch(void* const* d_in, const int* in_sizes, int n_in,
                              void* d_out, int out_size, void* d_ws, size_t ws_size,
                              hipStream_t stream)
{
    const float* action_feat = (const float*)d_in[1];
    const float* video_mask  = (const float*)d_in[3];
    const int*   captions    = (const int*)d_in[4];
    const float* capmask     = (const float*)d_in[5];
    const float* enc_img_W   = (const float*)d_in[6];
    const float* enc_img_b   = (const float*)d_in[7];
    const float* enc_mean_W  = (const float*)d_in[8];
    const float* enc_mean_b  = (const float*)d_in[9];
    const float* att_w       = (const float*)d_in[10];
    const float* att_Wa      = (const float*)d_in[11];
    const float* att_Ua      = (const float*)d_in[12];
    const float* att_ba      = (const float*)d_in[13];
    const float* Wemb        = (const float*)d_in[14];
    const float* embW        = (const float*)d_in[15];
    const float* embb        = (const float*)d_in[16];
    const float* W1ih        = (const float*)d_in[17];
    const float* W1hh        = (const float*)d_in[18];
    const float* b1ih        = (const float*)d_in[19];
    const float* b1hh        = (const float*)d_in[20];
    const float* W2ih        = (const float*)d_in[21];
    const float* W2hh        = (const float*)d_in[22];
    const float* b2ih        = (const float*)d_in[23];
    const float* b2hh        = (const float*)d_in[24];

    char* base = (char*)d_ws;
    size_t off = 0;
    auto alloc = [&](size_t bytes) {
        char* p = base + off;
        off = (off + bytes + 255) & ~(size_t)255;
        return p;
    };
    constexpr int BIG = 0x40000000;

    us* vf       = (us*)alloc((size_t)2560 * 1024 * 2);
    us* imgp     = (us*)alloc((size_t)2560 * 1024 * 2);
    float* fm    = (float*)alloc((size_t)64 * 2048 * 4);
    float* hw    = (float*)alloc((size_t)64 * 1024 * 4);
    us* hwPart   = (us*)alloc((size_t)64 * 64 * 1024 * 2);
    float* bsum1 = (float*)alloc(4096 * 4);
    float* bsum2 = (float*)alloc(4096 * 4);
    float* msum  = (float*)alloc(32 * 4);
    float* psumP = (float*)alloc((size_t)kNS * 250 * 64 * 4);
    float* tlogs = (float*)alloc((size_t)kNS * 64 * 4);
    us* Gemb     = (us*)alloc((size_t)kNS * 64 * 4096 * 2);
    us* x2p0 = (us*)alloc((size_t)64 * 2048 * 2);
    us* x2p1 = (us*)alloc((size_t)64 * 2048 * 2);
    float* c1    = (float*)alloc((size_t)64 * 1024 * 4);
    float* c2    = (float*)alloc((size_t)64 * 1024 * 4);
    size_t zlen  = (size_t)((char*)(c2 + 64 * 1024) - (char*)x2p0);

    us* x1p0 = (us*)alloc((size_t)64 * 2048 * 2);
    us* x1p1 = (us*)alloc((size_t)64 * 2048 * 2);
    us* h2hist = (us*)alloc((size_t)(kNS + 1) * 64 * 1024 * 2);
    us* embP = (us*)alloc((size_t)kNS * 64 * 1024 * 2);
    us* afP  = (us*)alloc((size_t)2560 * 2048 * 2);
    us* vfP  = (us*)alloc((size_t)2560 * 1024 * 2);
    us* fmP  = (us*)alloc((size_t)64 * 2048 * 2);
    us* WiP  = (us*)alloc((size_t)2048 * 1024 * 2);
    us* WmP  = (us*)alloc((size_t)2048 * 1024 * 2);
    us* WuaP = (us*)alloc((size_t)1024 * 1024 * 2);
    us* WaP  = (us*)alloc((size_t)1024 * 1024 * 2);
    us* WaE  = (us*)alloc((size_t)64 * 16 * 4 * 512 * 2);
    us* W1p  = (us*)alloc((size_t)3072 * 4096 * 2);
    us* W2p  = (us*)alloc((size_t)2048 * 4096 * 2);
    us* WvP  = (us*)alloc((size_t)1024 * 32000 * 2);
    if (off > ws_size) return;

    hipMemsetAsync(d_out, 0, 4, stream);
    hipMemsetAsync(x2p0, 0, zlen, stream);

    prep_mean<<<97, 256, 0, stream>>>(action_feat, fm, b1ih, b1hh, b2ih, b2hh,
                                      capmask, bsum1, bsum2, msum);
    pack_rm<<<dim3(16, 4), 256, 0, stream>>>(fm, 2048, BIG, nullptr, 0,
                                             4, 16, 64, 64, fmP);
    pack_rm<<<dim3(16, 160), 256, 0, stream>>>(action_feat, 2048, BIG, nullptr, 0,
                                               4, 16, 64, 64, afP);
    pack_rm<<<dim3(24, 256), 256, 0, stream>>>(W1ih, 2048, 2048, W1hh, 1024,
                                               4, 1024, 16, 96, W1p);
    pack_rm<<<dim3(16, 256), 256, 0, stream>>>(W2ih, 1024, 1024, W2hh, 1024,
                                               4, 1024, 16, 64, W2p);
    pack_sm4<<<1536, 256, 0, stream>>>(enc_img_W, enc_mean_W, att_Ua, att_Wa,
                                       WiP, WmP, WuaP, WaP);
    pack_wae<<<1024, 256, 0, stream>>>(att_Wa, WaE);
    pack_cm<<<dim3(250, 32), 256, 0, stream>>>(embW, WvP);
    pack_emb<<<960, 256, 0, stream>>>(Wemb, captions, embP);

    enc_gemm<64><<<dim3(16, 40), 256, 0, stream>>>(afP, WiP, enc_img_b, vf, vfP);
    p3_gemm<<<16, 256, 0, stream>>>(fmP, WmP, enc_mean_b, x1p0, h2hist);
    enc_gemm<32><<<dim3(16, 40), 256, 0, stream>>>(vfP, WuaP, att_ba, imgp, nullptr);
    gemb_gemm<<<1920, 256, 0, stream>>>(embP, W1p, Gemb);
    hwa_gemm<<<16, 512, 0, stream>>>(h2hist, WaP, hw);   // s=0 only

    int issued = 0;
    for (int s = 0; s < kNS; ++s) {
        us* x1c = (s & 1) ? x1p1 : x1p0;
        us* x1n = (s & 1) ? x1p0 : x1p1;
        us* x2c = (s & 1) ? x2p1 : x2p0;
        us* x2n = (s & 1) ? x2p0 : x2p1;
        int ready = (s >= 3) ? 250 * ((s - 3) / 3 + 1) : 0;
        int cnt = ready - issued;
        if (cnt > 84) cnt = 84;
        if (cnt < 0) cnt = 0;
        attn_logits<<<64 + cnt, 256, 0, stream>>>(
            (s == 0) ? hw : nullptr, hwPart, imgp, att_w, vf, video_mask, x1c,
            h2hist, WvP, embb, captions, psumP, tlogs, issued - 0 + (cnt ? 0 : 0));
        issued += cnt;
        gates_cell<64, 96, 32><<<64, 1024, 0, stream>>>(
            x1c, W1p, bsum1, Gemb + (size_t)s * 64 * 4096, c1,
            x1n, 1024, x2c, 0);
        gates2_cell<<<64, 1024, 0, stream>>>(
            x2c, W2p, bsum2, c2,
            x2n, 1024, h2hist + (size_t)(s + 1) * 65536, 0,
            (s < kNS - 1) ? hwPart : nullptr, WaE);
    }
    int rem = 2500 - issued;
    logits_tail<<<rem, 256, 0, stream>>>(h2hist, WvP, embb, captions,
                                         psumP, tlogs, issued);
    final_loss<<<kNS, 256, 0, stream>>>(psumP, tlogs, msum, (float*)d_out);
}

// Round 16
// 1804.349 us; speedup vs baseline: 1.1446x; 1.0014x over previous
//
#include <hip/hip_runtime.h>
#include <stdint.h>

constexpr int kB   = 64;
constexpr int kTV  = 40;
constexpr int kF   = 2048;
constexpr int kH   = 1024;
constexpr int kV   = 32000;
constexpr int kNS  = 30;
constexpr int kCAP = 31;

typedef __attribute__((ext_vector_type(8))) short bf16x8;
typedef __attribute__((ext_vector_type(4))) float f32x4;
typedef unsigned short us;

__device__ __forceinline__ float sigm(float x) { return 1.f / (1.f + __expf(-x)); }
__device__ __forceinline__ float tanh_fast(float x) {
    float e = __expf(2.f * x);
    return 1.f - 2.f / (e + 1.f);
}
__device__ __forceinline__ us f2bf(float x) {
    unsigned u = __float_as_uint(x);
    return (us)((u + 0x7fffu + ((u >> 16) & 1u)) >> 16);
}
__device__ __forceinline__ float bf2f(us u) {
    return __uint_as_float((unsigned)u << 16);
}

__device__ __forceinline__ void gl16(const us* g, us* lds) {
    __builtin_amdgcn_global_load_lds(
        (const __attribute__((address_space(1))) unsigned int*)(g),
        (__attribute__((address_space(3))) unsigned int*)(lds), 16, 0, 0);
}

template <int N>
__device__ __forceinline__ void waitv() {
    asm volatile("s_waitcnt vmcnt(%0)" :: "n"(N) : "memory");
}
__device__ __forceinline__ void barrier_raw() {
    __builtin_amdgcn_s_barrier();
    asm volatile("" ::: "memory");
}

// A-packed layout: [kt][ms][lane][j]; (row,col): ms=row>>4,
// lane=(row&15)+16*((kc>>2)&3), j=(kc&3)+4*(kc>>4), kc=col&31, kt=col>>5.
__device__ __forceinline__ void store_packedA(us* base, int row, int col, us v) {
    int kt = col >> 5, kc = col & 31, ms = row >> 4;
    int l = (row & 15) + (((kc >> 2) & 3) << 4);
    int j = (kc & 3) + ((kc >> 4) << 2);
    base[((((size_t)kt * 4 + ms) * 64 + l) << 3) + j] = v;
}

// ---------------- single-barrier 3-slot depth-2 MFMA K-loop ----------------
template <int NSPW, int KT>
__device__ __forceinline__ void mfma_kloop(
    const us* __restrict__ Ap, const us* __restrict__ Bp,
    us* Asm, us* Bsm, int w, int l, f32x4 acc[4][NSPW])
{
    constexpr int BSTEP = 2048 * NSPW;
    constexpr int LPT = 1 + NSPW;
    auto stage = [&](int t, int slot) {
        gl16(Ap + (size_t)t * 2048 + w * 512 + l * 8, Asm + slot * 2048 + w * 512);
#pragma unroll
        for (int i = 0; i < NSPW; ++i)
            gl16(Bp + (size_t)t * BSTEP + (w * NSPW + i) * 512 + l * 8,
                 Bsm + slot * BSTEP + (w * NSPW + i) * 512);
    };
    stage(0, 0);
    if (1 < KT) stage(1, 1);
#pragma unroll 1
    for (int t = 0; t < KT; ++t) {
        int slot = t % 3;
        if (t + 1 < KT) waitv<LPT>();
        else waitv<0>();
        barrier_raw();
        if (t + 2 < KT) stage(t + 2, (t + 2) % 3);
        bf16x8 bfr[NSPW], afr[4];
#pragma unroll
        for (int i = 0; i < NSPW; ++i)
            bfr[i] = *(const bf16x8*)(Bsm + slot * BSTEP + ((w * NSPW + i) * 64 + l) * 8);
#pragma unroll
        for (int ms = 0; ms < 4; ++ms)
            afr[ms] = *(const bf16x8*)(Asm + slot * 2048 + (ms * 64 + l) * 8);
#pragma unroll
        for (int ms = 0; ms < 4; ++ms)
#pragma unroll
            for (int i = 0; i < NSPW; ++i)
                acc[ms][i] = __builtin_amdgcn_mfma_f32_16x16x32_bf16(
                    afr[ms], bfr[i], acc[ms][i], 0, 0, 0);
        __builtin_amdgcn_sched_barrier(0);
    }
}

// ---------------- prep: feat mean + bias sums + mask sums ----------------
__global__ __launch_bounds__(256) void prep_mean(
    const float* __restrict__ af, float* __restrict__ fm,
    const float* __restrict__ bih1, const float* __restrict__ bhh1,
    const float* __restrict__ bih2, const float* __restrict__ bhh2,
    const float* __restrict__ capmask,
    float* __restrict__ bsum1, float* __restrict__ bsum2, float* __restrict__ msum)
{
    int tid = threadIdx.x;
    if (blockIdx.x < 64) {
        int b = blockIdx.x;
        const float* base = af + (size_t)b * kTV * kF;
        float a[8] = {};
        for (int t = 0; t < kTV; ++t) {
            const float* rp = base + (size_t)t * kF + tid * 8;
            float4 v0 = *(const float4*)rp;
            float4 v1 = *(const float4*)(rp + 4);
            a[0] += v0.x; a[1] += v0.y; a[2] += v0.z; a[3] += v0.w;
            a[4] += v1.x; a[5] += v1.y; a[6] += v1.z; a[7] += v1.w;
        }
        float* op = fm + (size_t)b * kF + tid * 8;
#pragma unroll
        for (int j = 0; j < 8; ++j) op[j] = a[j] * (1.f / kTV);
    } else {
        int g = (blockIdx.x - 64) * 256 + tid;
        if (g < 4096) bsum1[g] = bih1[g] + bhh1[g];
        else if (g < 8192) { int j = g - 4096; bsum2[j] = bih2[j] + bhh2[j]; }
        else if (g < 8192 + kNS) {
            int t = g - 8192;
            float s = 0.f;
            for (int b = 0; b < kB; ++b) s += capmask[b * kCAP + t + 1];
            msum[t] = s;
        }
    }
}

// ---------------- packing: row-major source(s) -> fragment tiles ----------------
__global__ __launch_bounds__(256) void pack_rm(
    const float* __restrict__ p0, int ld0, int ksplit,
    const float* __restrict__ p1, int ld1,
    int NGRP, int GS, int HS, int KT,
    us* __restrict__ out)
{
    __shared__ us tile[16][136];
    int kb = blockIdx.x * 128;
    int grp = blockIdx.y;
    int row0 = (grp % NGRP) * GS + (grp / NGRP) * HS;
    int tid = threadIdx.x;
    int r = tid >> 5, c4 = (tid & 31) * 4;
#pragma unroll
    for (int pass = 0; pass < 2; ++pass) {
        int rr = r + pass * 8;
        int row = row0 + rr;
        int k = kb + c4;
        float4 v;
        if (k < ksplit) v = *(const float4*)(p0 + (size_t)row * ld0 + k);
        else            v = *(const float4*)(p1 + (size_t)row * ld1 + (k - ksplit));
        ushort4 o; o.x = f2bf(v.x); o.y = f2bf(v.y); o.z = f2bf(v.z); o.w = f2bf(v.w);
        *(ushort4*)&tile[rr][c4] = o;
    }
    __syncthreads();
    int ktl = tid >> 6, l = tid & 63, ul = l & 15, q = (l >> 4) & 3;
    __align__(16) us o2[8];
#pragma unroll
    for (int j = 0; j < 8; ++j) {
        int kc = (j & 3) + q * 4 + ((j >> 2) << 4);
        o2[j] = tile[ul][ktl * 32 + kc];
    }
    int kt = (kb >> 5) + ktl;
    size_t base = (((size_t)(grp / NGRP) * KT + kt) * NGRP + (grp % NGRP)) * 512;
    *(uint4*)(out + base + (size_t)l * 8) = *(const uint4*)o2;
}

// vocab [K][32000] -> B tiles S=8
__global__ __launch_bounds__(256) void pack_cm(const float* __restrict__ W,
                                               us* __restrict__ out)
{
    __shared__ us tile[32][136];
    int n0 = blockIdx.x * 128, k0 = blockIdx.y * 32;
    int tid = threadIdx.x;
    int r = tid >> 5, c4 = (tid & 31) * 4;
#pragma unroll
    for (int pass = 0; pass < 4; ++pass) {
        int rr = r + pass * 8;
        float4 v = *(const float4*)(W + (size_t)(k0 + rr) * kV + n0 + c4);
        ushort4 o; o.x = f2bf(v.x); o.y = f2bf(v.y); o.z = f2bf(v.z); o.w = f2bf(v.w);
        *(ushort4*)&tile[rr][c4] = o;
    }
    __syncthreads();
    int ns = tid >> 5, lp = (tid & 31) * 2;
    size_t base = (((size_t)blockIdx.x * 32 + blockIdx.y) * 8 + ns) * 512;
    __align__(16) us o2[16];
#pragma unroll
    for (int li = 0; li < 2; ++li) {
        int l = lp + li, ul = l & 15, q = (l >> 4) & 3;
#pragma unroll
        for (int j = 0; j < 8; ++j) {
            int kc = (j & 3) + q * 4 + ((j >> 2) << 4);
            o2[li * 8 + j] = tile[kc][ns * 16 + ul];
        }
    }
    *(uint4*)(out + base + lp * 8) = *(const uint4*)&o2[0];
    *(uint4*)(out + base + lp * 8 + 8) = *(const uint4*)&o2[8];
}

// 4 small [K][1024] weights -> B tiles S=4, coalesced LDS-staged
__global__ __launch_bounds__(256) void pack_sm4(
    const float* __restrict__ Wi, const float* __restrict__ Wm,
    const float* __restrict__ Wua, const float* __restrict__ Wa,
    us* __restrict__ oi, us* __restrict__ om,
    us* __restrict__ oua, us* __restrict__ oa)
{
    int bid = blockIdx.x;
    const float* W; us* out; int KT, rel;
    if (bid < 512)       { W = Wi;  out = oi;  KT = 64; rel = bid; }
    else if (bid < 1024) { W = Wm;  out = om;  KT = 64; rel = bid - 512; }
    else if (bid < 1280) { W = Wua; out = oua; KT = 32; rel = bid - 1024; }
    else                 { W = Wa;  out = oa;  KT = 32; rel = bid - 1280; }
    int bx = rel & 7, by = rel >> 3;
    __shared__ us tile[32][136];
    int n0 = bx * 128, k0 = by * 32;
    int tid = threadIdx.x;
    int r = tid >> 5, c4 = (tid & 31) * 4;
#pragma unroll
    for (int pass = 0; pass < 4; ++pass) {
        int rr = r + pass * 8;
        float4 v = *(const float4*)(W + (size_t)(k0 + rr) * 1024 + n0 + c4);
        ushort4 o; o.x = f2bf(v.x); o.y = f2bf(v.y); o.z = f2bf(v.z); o.w = f2bf(v.w);
        *(ushort4*)&tile[rr][c4] = o;
    }
    __syncthreads();
    int ns = tid >> 5, lp = (tid & 31) * 2;
    int nb64 = bx * 2 + (ns >> 2), ns4 = ns & 3;
    size_t base = (((size_t)nb64 * KT + by) * 4 + ns4) * 512;
    __align__(16) us o2[16];
#pragma unroll
    for (int li = 0; li < 2; ++li) {
        int l = lp + li, ul = l & 15, q = (l >> 4) & 3;
#pragma unroll
        for (int j = 0; j < 8; ++j) {
            int kc = (j & 3) + q * 4 + ((j >> 2) << 4);
            o2[li * 8 + j] = tile[kc][ns * 16 + ul];
        }
    }
    *(uint4*)(out + base + lp * 8) = *(const uint4*)&o2[0];
    *(uint4*)(out + base + lp * 8 + 8) = *(const uint4*)&o2[8];
}

// Wa -> WaE[nb][cb][ns][64][8]: K=32 B-frags, k 0-15 = Wa rows nb*16+k, k>=16 zero
__global__ __launch_bounds__(256) void pack_wae(const float* __restrict__ Wa,
                                                us* __restrict__ WaE)
{
    int nb = blockIdx.x >> 4, cb = blockIdx.x & 15;
    int tid = threadIdx.x;
    int ns = tid >> 6, l = tid & 63;
    int ul = l & 15, q = (l >> 4) & 3;
    int col = cb * 64 + ns * 16 + ul;
    __align__(16) us o[8];
#pragma unroll
    for (int j = 0; j < 4; ++j) {
        int k = (j & 3) + q * 4;               // 0..15
        o[j] = f2bf(Wa[(size_t)(nb * 16 + k) * kH + col]);
    }
    o[4] = 0; o[5] = 0; o[6] = 0; o[7] = 0;
    size_t base = (((size_t)(nb * 16 + cb)) * 4 + ns) * 512;
    *(uint4*)(WaE + base + (size_t)l * 8) = *(const uint4*)o;
}

// per-step emb rows -> A-packed tiles: embP[s][kt32][ms4][512]
__global__ __launch_bounds__(256) void pack_emb(
    const float* __restrict__ Wemb, const int* __restrict__ captions,
    us* __restrict__ embP)
{
    __shared__ us tile[16][136];
    int rel = blockIdx.x;              // 960 = 30 s x 4 rg x 8 kb
    int s = rel / 32, rem = rel % 32;
    int rg = rem & 3, kb8 = rem >> 2;
    int tid = threadIdx.x;
    int r = tid >> 5, c4 = (tid & 31) * 4;
#pragma unroll
    for (int pass = 0; pass < 2; ++pass) {
        int rr = r + pass * 8;
        int b = rg * 16 + rr;
        int word = captions[b * kCAP + s];
        float4 v = *(const float4*)(Wemb + (size_t)word * kH + kb8 * 128 + c4);
        ushort4 o; o.x = f2bf(v.x); o.y = f2bf(v.y); o.z = f2bf(v.z); o.w = f2bf(v.w);
        *(ushort4*)&tile[rr][c4] = o;
    }
    __syncthreads();
    int ktl = tid >> 6, l = tid & 63, ul = l & 15, q = (l >> 4) & 3;
    __align__(16) us o2[8];
#pragma unroll
    for (int j = 0; j < 8; ++j) {
        int kc = (j & 3) + q * 4 + ((j >> 2) << 4);
        o2[j] = tile[ul][ktl * 32 + kc];
    }
    int kt = kb8 * 4 + ktl;
    size_t base = (((size_t)s * 32 + kt) * 4 + rg) * 512;
    *(uint4*)(embP + base + (size_t)l * 8) = *(const uint4*)o2;
}

// ---------------- encoder GEMM (LDS-staged), bf16 outF ----------------
template <int KT>
__global__ __launch_bounds__(256) void enc_gemm(
    const us* __restrict__ Ap, const us* __restrict__ Bp,
    const float* __restrict__ bias, us* __restrict__ outF,
    us* __restrict__ outP)
{
    __shared__ us Asm[3][2048];
    __shared__ us Bsm[3][2048];
    int tid = threadIdx.x, w = tid >> 6, l = tid & 63;
    int nb = blockIdx.x, mb = blockIdx.y;
    f32x4 acc[4][1] = {};
    mfma_kloop<1, KT>(Ap + (size_t)mb * KT * 2048, Bp + (size_t)nb * KT * 2048,
                      &Asm[0][0], &Bsm[0][0], w, l, acc);
    int ul = l & 15, sg = l >> 4;
    int n = nb * 64 + w * 16 + ul;
    float bv = bias[n];
#pragma unroll
    for (int ms = 0; ms < 4; ++ms)
#pragma unroll
        for (int r = 0; r < 4; ++r) {
            int rl = ms * 16 + sg * 4 + r;
            int row = mb * 64 + rl;
            float v = acc[ms][0][r] + bv;
            outF[(size_t)row * kH + n] = f2bf(v);
            if (outP) store_packedA(outP + (size_t)mb * 65536, rl, n, f2bf(v));
        }
}

// P3: feat_h -> x1p0 h1-slot (col 1024+) and h2hist[0]
__global__ __launch_bounds__(256) void p3_gemm(
    const us* __restrict__ Ap, const us* __restrict__ Bp,
    const float* __restrict__ bias, us* __restrict__ xcat1p,
    us* __restrict__ h2hist0)
{
    __shared__ us Asm[3][2048];
    __shared__ us Bsm[3][2048];
    int tid = threadIdx.x, w = tid >> 6, l = tid & 63;
    int nb = blockIdx.x;
    f32x4 acc[4][1] = {};
    mfma_kloop<1, 64>(Ap, Bp + (size_t)nb * 64 * 2048, &Asm[0][0], &Bsm[0][0], w, l, acc);
    int ul = l & 15, sg = l >> 4;
    int n = nb * 64 + w * 16 + ul;
    float bv = bias[n];
#pragma unroll
    for (int ms = 0; ms < 4; ++ms)
#pragma unroll
        for (int r = 0; r < 4; ++r) {
            int row = ms * 16 + sg * 4 + r;
            us hb = f2bf(acc[ms][0][r] + bv);
            store_packedA(xcat1p, row, 1024 + n, hb);
            store_packedA(h2hist0, row, n, hb);
        }
}

// Gemb[s] = emb(s) @ W1ih[:, 0:1024] (bf16 out, gate-interleaved cols)
__global__ __launch_bounds__(256) void gemb_gemm(
    const us* __restrict__ embP, const us* __restrict__ W1p,
    us* __restrict__ Gemb)
{
    __shared__ us Asm[3][2048];
    __shared__ us Bsm[3][2048];
    int rel = blockIdx.x;              // 1920 = 30 s x 64 nb
    int s = rel >> 6, nb = rel & 63;
    int tid = threadIdx.x, w = tid >> 6, l = tid & 63;
    f32x4 acc[4][1] = {};
    mfma_kloop<1, 32>(embP + (size_t)s * 65536, W1p + (size_t)nb * 96 * 2048,
                      &Asm[0][0], &Bsm[0][0], w, l, acc);
    int ul = l & 15, sg = l >> 4;
    int n = nb * 64 + w * 16 + ul;
#pragma unroll
    for (int ms = 0; ms < 4; ++ms)
#pragma unroll
        for (int r = 0; r < 4; ++r) {
            int row = ms * 16 + sg * 4 + r;
            Gemb[((size_t)s * 64 + row) * 4096 + n] = f2bf(acc[ms][0][r]);
        }
}

// ---------------- hwa for s=0 only: hw = h2hist[0] @ att_Wa ----------------
__global__ __launch_bounds__(512) void hwa_gemm(
    const us* __restrict__ h2p, const us* __restrict__ WaP,
    float* __restrict__ hw)
{
    __shared__ __align__(16) char smem[49152];
    float* rsum = (float*)smem;
    int tid = threadIdx.x, w = tid >> 6, l = tid & 63, nb = blockIdx.x;
    int h = w >> 2, w4 = w & 3;
    us* Asm = (us*)(smem + h * 24576);
    us* Bsm = Asm + 6144;
    f32x4 acc[4][1] = {};
    mfma_kloop<1, 16>(h2p + (size_t)h * 16 * 2048,
                      WaP + (size_t)nb * 32 * 2048 + (size_t)h * 16 * 2048,
                      Asm, Bsm, w4, l, acc);
    int ul = l & 15, sg = l >> 4;
    __syncthreads();
    if (h == 1) {
#pragma unroll
        for (int ms = 0; ms < 4; ++ms)
#pragma unroll
            for (int r = 0; r < 4; ++r)
                rsum[((w4 * 64) + ms * 16 + sg * 4 + r) * 17 + ul] = acc[ms][0][r];
    }
    __syncthreads();
    if (h == 0) {
        int n = nb * 64 + w4 * 16 + ul;
#pragma unroll
        for (int ms = 0; ms < 4; ++ms)
#pragma unroll
            for (int r = 0; r < 4; ++r) {
                int row = ms * 16 + sg * 4 + r;
                hw[(size_t)row * kH + n] =
                    acc[ms][0][r] + rsum[((w4 * 64) + row) * 17 + ul];
            }
    }
}

// ---------------- fused attention + appended logits chunk ----------------
__global__ __launch_bounds__(256) void attn_logits(
    const float* __restrict__ hw0, const us* __restrict__ hwP,
    const us* __restrict__ imgp, const float* __restrict__ attw,
    const us* __restrict__ vf, const float* __restrict__ vmask,
    us* __restrict__ xcat1p,
    const us* __restrict__ h2hist, const us* __restrict__ WvP,
    const float* __restrict__ embb, const int* __restrict__ captions,
    float* __restrict__ psumP, float* __restrict__ tlogs, int lgStart)
{
    __shared__ __align__(16) char smem[63488];
    int tid = threadIdx.x, w = tid >> 6, l = tid & 63, ul = l & 15, lsg = l >> 4;
    if (blockIdx.x >= 64) {
        us* Asm = (us*)smem;                      // [3 si][3 slot][2048]
        us* Bsm = (us*)(smem + 36864);            // [3][4096]
        float* rsum = (float*)(smem + 61440);     // [4][64]
        int* stgt = (int*)(smem + 62464);         // [3][64]
        int lb = lgStart + (int)blockIdx.x - 64;
        int g = lb / 250, nb = lb % 250;
        int s0 = g * 3;
        if (tid < 64)
#pragma unroll
            for (int si = 0; si < 3; ++si)
                stgt[si * 64 + tid] = captions[tid * kCAP + s0 + si + 1];
        const us* Ab0 = h2hist + (size_t)(s0 + 1) * 65536;
        const us* Ab1 = h2hist + (size_t)(s0 + 2) * 65536;
        const us* Ab2 = h2hist + (size_t)(s0 + 3) * 65536;
        const us* Bb  = WvP + (size_t)nb * 32 * 4096;
        auto stage = [&](int t, int slot) {
            gl16(Ab0 + (size_t)t * 2048 + w * 512 + l * 8,
                 Asm + (0 * 3 + slot) * 2048 + w * 512);
            gl16(Ab1 + (size_t)t * 2048 + w * 512 + l * 8,
                 Asm + (1 * 3 + slot) * 2048 + w * 512);
            gl16(Ab2 + (size_t)t * 2048 + w * 512 + l * 8,
                 Asm + (2 * 3 + slot) * 2048 + w * 512);
#pragma unroll
            for (int i = 0; i < 2; ++i)
                gl16(Bb + (size_t)t * 4096 + (w * 2 + i) * 512 + l * 8,
                     Bsm + slot * 4096 + (w * 2 + i) * 512);
        };
        f32x4 acc[3][4][2] = {};
        stage(0, 0); stage(1, 1);
#pragma unroll 1
        for (int t = 0; t < 32; ++t) {
            int slot = t % 3;
            if (t + 1 < 32) waitv<5>();
            else waitv<0>();
            barrier_raw();
            if (t + 2 < 32) stage(t + 2, (t + 2) % 3);
            bf16x8 b0 = *(const bf16x8*)(Bsm + slot * 4096 + ((w * 2 + 0) * 64 + l) * 8);
            bf16x8 b1 = *(const bf16x8*)(Bsm + slot * 4096 + ((w * 2 + 1) * 64 + l) * 8);
#pragma unroll
            for (int ms = 0; ms < 4; ++ms)
#pragma unroll
                for (int si = 0; si < 3; ++si) {
                    bf16x8 a = *(const bf16x8*)(Asm + (si * 3 + slot) * 2048 +
                                                (ms * 64 + l) * 8);
                    acc[si][ms][0] = __builtin_amdgcn_mfma_f32_16x16x32_bf16(
                        a, b0, acc[si][ms][0], 0, 0, 0);
                    acc[si][ms][1] = __builtin_amdgcn_mfma_f32_16x16x32_bf16(
                        a, b1, acc[si][ms][1], 0, 0, 0);
                }
            __builtin_amdgcn_sched_barrier(0);
        }
        int n0 = nb * 128 + (2 * w + 0) * 16 + ul;
        int n1 = nb * 128 + (2 * w + 1) * 16 + ul;
        float e0 = embb[n0], e1 = embb[n1];
#pragma unroll
        for (int si = 0; si < 3; ++si) {
            float ls[4][4];
#pragma unroll
            for (int ms = 0; ms < 4; ++ms)
#pragma unroll
                for (int r = 0; r < 4; ++r) {
                    int row = ms * 16 + lsg * 4 + r;
                    float v0 = acc[si][ms][0][r] + e0, v1 = acc[si][ms][1][r] + e1;
                    ls[ms][r] = __expf(v0) + __expf(v1);
                    if (n0 == stgt[si * 64 + row]) tlogs[(s0 + si) * 64 + row] = v0;
                    if (n1 == stgt[si * 64 + row]) tlogs[(s0 + si) * 64 + row] = v1;
                }
#pragma unroll
            for (int m = 1; m < 16; m <<= 1)
#pragma unroll
                for (int ms = 0; ms < 4; ++ms)
#pragma unroll
                    for (int r = 0; r < 4; ++r)
                        ls[ms][r] += __shfl_xor(ls[ms][r], m);
            if (ul == 0)
#pragma unroll
                for (int ms = 0; ms < 4; ++ms)
#pragma unroll
                    for (int r = 0; r < 4; ++r)
                        rsum[w * 64 + ms * 16 + lsg * 4 + r] = ls[ms][r];
            __syncthreads();
            if (tid < 64)
                psumP[((size_t)(s0 + si) * 250 + nb) * 64 + tid] =
                    rsum[0 * 64 + tid] + rsum[1 * 64 + tid] +
                    rsum[2 * 64 + tid] + rsum[3 * 64 + tid];
            __syncthreads();
        }
        return;
    }
    float* hwv = (float*)smem;
    float* es = (float*)(smem + 4096);
    int b = blockIdx.x;
    if (hw0) {
        for (int i = tid; i < kH; i += 256) hwv[i] = hw0[(size_t)b * kH + i];
    } else {
        int c4 = tid * 4;
        float a0 = 0.f, a1 = 0.f, a2 = 0.f, a3 = 0.f;
        for (int nb = 0; nb < 64; ++nb) {
            ushort4 v = *(const ushort4*)(hwP + ((size_t)nb * 64 + b) * 1024 + c4);
            a0 += bf2f(v.x); a1 += bf2f(v.y); a2 += bf2f(v.z); a3 += bf2f(v.w);
        }
        hwv[c4 + 0] = a0; hwv[c4 + 1] = a1; hwv[c4 + 2] = a2; hwv[c4 + 3] = a3;
    }
    __syncthreads();
    for (int t = w; t < kTV; t += 4) {
        const us* ip = imgp + ((size_t)b * kTV + t) * kH;
        float p = 0.f;
#pragma unroll
        for (int hh = 0; hh < 16; ++hh) {
            int h = hh * 64 + l;
            p += tanh_fast(hwv[h] + bf2f(ip[h])) * attw[h];
        }
        for (int off = 32; off; off >>= 1) p += __shfl_down(p, off);
        if (l == 0) es[t] = p;
    }
    __syncthreads();
    float mx = -1e30f;
    for (int t = 0; t < kTV; ++t) mx = fmaxf(mx, es[t]);
    const float* vm = vmask + b * kTV;
    float den = 0.f;
    for (int t = 0; t < kTV; ++t) den += vm[t] * __expf(es[t] - mx);
    den = den + (den == 0.f ? 1.f : 0.f) + 1e-9f;
    int h0 = tid * 4;
    float a0 = 0.f, a1 = 0.f, a2 = 0.f, a3 = 0.f;
    for (int t = 0; t < kTV; ++t) {
        float wgt = vm[t] * __expf(es[t] - mx) / den;
        ushort4 v = *(const ushort4*)(vf + ((size_t)b * kTV + t) * kH + h0);
        a0 += wgt * bf2f(v.x); a1 += wgt * bf2f(v.y);
        a2 += wgt * bf2f(v.z); a3 += wgt * bf2f(v.w);
    }
    store_packedA(xcat1p, b, h0 + 0, f2bf(a0));
    store_packedA(xcat1p, b, h0 + 1, f2bf(a1));
    store_packedA(xcat1p, b, h0 + 2, f2bf(a2));
    store_packedA(xcat1p, b, h0 + 3, f2bf(a3));
}

// ---------------- logits tail (remaining blocks after the loop) ----------------
__global__ __launch_bounds__(256) void logits_tail(
    const us* __restrict__ h2hist, const us* __restrict__ WvP,
    const float* __restrict__ embb, const int* __restrict__ captions,
    float* __restrict__ psumP, float* __restrict__ tlogs, int lgStart)
{
    __shared__ us Asm[3][3][2048];
    __shared__ us Bsm[3][4096];
    __shared__ float rsum[4][64];
    __shared__ int stgt[3][64];
    int lb = lgStart + (int)blockIdx.x;
    int g = lb / 250, nb = lb % 250;
    int s0 = g * 3;
    int tid = threadIdx.x, w = tid >> 6, l = tid & 63, ul = l & 15, lsg = l >> 4;
    if (tid < 64)
#pragma unroll
        for (int si = 0; si < 3; ++si)
            stgt[si][tid] = captions[tid * kCAP + s0 + si + 1];
    const us* Ab0 = h2hist + (size_t)(s0 + 1) * 65536;
    const us* Ab1 = h2hist + (size_t)(s0 + 2) * 65536;
    const us* Ab2 = h2hist + (size_t)(s0 + 3) * 65536;
    const us* Bb  = WvP + (size_t)nb * 32 * 4096;
    auto stage = [&](int t, int slot) {
        gl16(Ab0 + (size_t)t * 2048 + w * 512 + l * 8, &Asm[0][slot][w * 512]);
        gl16(Ab1 + (size_t)t * 2048 + w * 512 + l * 8, &Asm[1][slot][w * 512]);
        gl16(Ab2 + (size_t)t * 2048 + w * 512 + l * 8, &Asm[2][slot][w * 512]);
#pragma unroll
        for (int i = 0; i < 2; ++i)
            gl16(Bb + (size_t)t * 4096 + (w * 2 + i) * 512 + l * 8,
                 &Bsm[slot][(w * 2 + i) * 512]);
    };
    f32x4 acc[3][4][2] = {};
    stage(0, 0); stage(1, 1);
#pragma unroll 1
    for (int t = 0; t < 32; ++t) {
        int slot = t % 3;
        if (t + 1 < 32) waitv<5>();
        else waitv<0>();
        barrier_raw();
        if (t + 2 < 32) stage(t + 2, (t + 2) % 3);
        bf16x8 b0 = *(const bf16x8*)&Bsm[slot][((w * 2 + 0) * 64 + l) * 8];
        bf16x8 b1 = *(const bf16x8*)&Bsm[slot][((w * 2 + 1) * 64 + l) * 8];
#pragma unroll
        for (int ms = 0; ms < 4; ++ms)
#pragma unroll
            for (int si = 0; si < 3; ++si) {
                bf16x8 a = *(const bf16x8*)&Asm[si][slot][(ms * 64 + l) * 8];
                acc[si][ms][0] = __builtin_amdgcn_mfma_f32_16x16x32_bf16(
                    a, b0, acc[si][ms][0], 0, 0, 0);
                acc[si][ms][1] = __builtin_amdgcn_mfma_f32_16x16x32_bf16(
                    a, b1, acc[si][ms][1], 0, 0, 0);
            }
        __builtin_amdgcn_sched_barrier(0);
    }
    int n0 = nb * 128 + (2 * w + 0) * 16 + ul;
    int n1 = nb * 128 + (2 * w + 1) * 16 + ul;
    float e0 = embb[n0], e1 = embb[n1];
#pragma unroll
    for (int si = 0; si < 3; ++si) {
        float ls[4][4];
#pragma unroll
        for (int ms = 0; ms < 4; ++ms)
#pragma unroll
            for (int r = 0; r < 4; ++r) {
                int row = ms * 16 + lsg * 4 + r;
                float v0 = acc[si][ms][0][r] + e0, v1 = acc[si][ms][1][r] + e1;
                ls[ms][r] = __expf(v0) + __expf(v1);
                if (n0 == stgt[si][row]) tlogs[(s0 + si) * 64 + row] = v0;
                if (n1 == stgt[si][row]) tlogs[(s0 + si) * 64 + row] = v1;
            }
#pragma unroll
        for (int m = 1; m < 16; m <<= 1)
#pragma unroll
            for (int ms = 0; ms < 4; ++ms)
#pragma unroll
                for (int r = 0; r < 4; ++r)
                    ls[ms][r] += __shfl_xor(ls[ms][r], m);
        if (ul == 0)
#pragma unroll
            for (int ms = 0; ms < 4; ++ms)
#pragma unroll
                for (int r = 0; r < 4; ++r)
                    rsum[w][ms * 16 + lsg * 4 + r] = ls[ms][r];
        __syncthreads();
        if (tid < 64)
            psumP[((size_t)(s0 + si) * 250 + nb) * 64 + tid] =
                rsum[0][tid] + rsum[1][tid] + rsum[2][tid] + rsum[3][tid];
        __syncthreads();
    }
}

// ---------------- gates1: GEMM + LSTM cell (1024 thr, staged 4-way K-split) ----------------
template <int KT, int BSTR, int KOFF>
__global__ __launch_bounds__(1024) void gates_cell(
    const us* __restrict__ Ap, const us* __restrict__ Bp,
    const float* __restrict__ bsum, const us* __restrict__ gemb,
    float* __restrict__ cbuf,
    us* __restrict__ dA, int ofsA, us* __restrict__ dB, int ofsB)
{
    __shared__ __align__(16) char smem[98304];
    float* gsm = (float*)smem;
    constexpr int KQ = KT / 4;
    int tid = threadIdx.x, w16 = tid >> 6, l = tid & 63, nb = blockIdx.x;
    int g = w16 >> 2, w4 = w16 & 3;
    us* Asm = (us*)(smem + g * 24576);
    us* Bsm = Asm + 6144;
    f32x4 acc[4][1] = {};
    mfma_kloop<1, KQ>(Ap + (size_t)g * KQ * 2048,
                      Bp + (size_t)nb * BSTR * 2048 + (size_t)(KOFF + g * KQ) * 2048,
                      Asm, Bsm, w4, l, acc);
    int ul = l & 15, sg = l >> 4;
    int sl = (g & 1) * 4 + w4;
    float bv = (g == 0) ? bsum[w4 * 1024 + nb * 16 + ul] : 0.f;
    __syncthreads();
    if (g < 2) {
#pragma unroll
        for (int ms = 0; ms < 4; ++ms)
#pragma unroll
            for (int r = 0; r < 4; ++r)
                gsm[(sl * 64 + ms * 16 + sg * 4 + r) * 17 + ul] = acc[ms][0][r] + bv;
    }
    __syncthreads();
    if (g >= 2) {
#pragma unroll
        for (int ms = 0; ms < 4; ++ms)
#pragma unroll
            for (int r = 0; r < 4; ++r)
                gsm[(sl * 64 + ms * 16 + sg * 4 + r) * 17 + ul] += acc[ms][0][r];
    }
    __syncthreads();
    {
        int row = tid >> 4, uc = tid & 15, u = nb * 16 + uc;
        float ge0 = 0.f, ge1 = 0.f, ge2 = 0.f, ge3 = 0.f;
        if (gemb) {
            const us* gp = gemb + (size_t)row * 4096 + nb * 64 + uc;
            ge0 = bf2f(gp[0]); ge1 = bf2f(gp[16]);
            ge2 = bf2f(gp[32]); ge3 = bf2f(gp[48]);
        }
        float gi = gsm[((0 * 64) + row) * 17 + uc] + gsm[((4 * 64) + row) * 17 + uc] + ge0;
        float gf = gsm[((1 * 64) + row) * 17 + uc] + gsm[((5 * 64) + row) * 17 + uc] + ge1;
        float gg = gsm[((2 * 64) + row) * 17 + uc] + gsm[((6 * 64) + row) * 17 + uc] + ge2;
        float go = gsm[((3 * 64) + row) * 17 + uc] + gsm[((7 * 64) + row) * 17 + uc] + ge3;
        float c = sigm(gf) * cbuf[(size_t)row * kH + u] + sigm(gi) * tanh_fast(gg);
        cbuf[(size_t)row * kH + u] = c;
        us hb = f2bf(sigm(go) * tanh_fast(c));
        store_packedA(dA, row, ofsA + u, hb);
        store_packedA(dB, row, ofsB + u, hb);
    }
}

// ---------------- gates2: GEMM + cell + distributed-hwa partial epilogue (bf16) ----------------
__global__ __launch_bounds__(1024) void gates2_cell(
    const us* __restrict__ Ap, const us* __restrict__ Bp,
    const float* __restrict__ bsum, float* __restrict__ cbuf,
    us* __restrict__ dA, int ofsA, us* __restrict__ dB, int ofsB,
    us* __restrict__ hwPart, const us* __restrict__ WaE)
{
    __shared__ __align__(16) char smem[98304];
    float* gsm = (float*)smem;
    us* hA = (us*)(smem + 40960);
    constexpr int KQ = 16;
    int tid = threadIdx.x, w16 = tid >> 6, l = tid & 63, nb = blockIdx.x;
    int g = w16 >> 2, w4 = w16 & 3;
    us* Asm = (us*)(smem + g * 24576);
    us* Bsm = Asm + 6144;
    f32x4 acc[4][1] = {};
    mfma_kloop<1, KQ>(Ap + (size_t)g * KQ * 2048,
                      Bp + (size_t)nb * 64 * 2048 + (size_t)(g * KQ) * 2048,
                      Asm, Bsm, w4, l, acc);
    int ul = l & 15, sg = l >> 4;
    int sl = (g & 1) * 4 + w4;
    float bv = (g == 0) ? bsum[w4 * 1024 + nb * 16 + ul] : 0.f;
    __syncthreads();
    if (g < 2) {
#pragma unroll
        for (int ms = 0; ms < 4; ++ms)
#pragma unroll
            for (int r = 0; r < 4; ++r)
                gsm[(sl * 64 + ms * 16 + sg * 4 + r) * 17 + ul] = acc[ms][0][r] + bv;
    }
    __syncthreads();
    if (g >= 2) {
#pragma unroll
        for (int ms = 0; ms < 4; ++ms)
#pragma unroll
            for (int r = 0; r < 4; ++r)
                gsm[(sl * 64 + ms * 16 + sg * 4 + r) * 17 + ul] += acc[ms][0][r];
    }
    __syncthreads();
    int row = tid >> 4, uc = tid & 15, u = nb * 16 + uc;
    {
        float gi = gsm[((0 * 64) + row) * 17 + uc] + gsm[((4 * 64) + row) * 17 + uc];
        float gf = gsm[((1 * 64) + row) * 17 + uc] + gsm[((5 * 64) + row) * 17 + uc];
        float gg = gsm[((2 * 64) + row) * 17 + uc] + gsm[((6 * 64) + row) * 17 + uc];
        float go = gsm[((3 * 64) + row) * 17 + uc] + gsm[((7 * 64) + row) * 17 + uc];
        float c = sigm(gf) * cbuf[(size_t)row * kH + u] + sigm(gi) * tanh_fast(gg);
        cbuf[(size_t)row * kH + u] = c;
        us hb = f2bf(sigm(go) * tanh_fast(c));
        store_packedA(dA, row, ofsA + u, hb);
        store_packedA(dB, row, ofsB + u, hb);
        if (hwPart) {
            *(unsigned*)(hA + tid * 2) = 0;
            __syncthreads();
            int lpos = (row & 15) + (((uc >> 2) & 3) << 4);
            hA[((((row >> 4) * 64) + lpos) << 3) + (uc & 3)] = hb;
            __syncthreads();
            int cb = w16;
            f32x4 hacc[4][4] = {};
            bf16x8 afr[4];
#pragma unroll
            for (int ms = 0; ms < 4; ++ms)
                afr[ms] = *(const bf16x8*)(hA + (ms * 64 + l) * 8);
#pragma unroll
            for (int ns = 0; ns < 4; ++ns) {
                bf16x8 bfr = *(const bf16x8*)(WaE +
                    ((((size_t)(nb * 16 + cb)) * 4 + ns) << 9) + l * 8);
#pragma unroll
                for (int ms = 0; ms < 4; ++ms)
                    hacc[ms][ns] = __builtin_amdgcn_mfma_f32_16x16x32_bf16(
                        afr[ms], bfr, hacc[ms][ns], 0, 0, 0);
            }
#pragma unroll
            for (int ms = 0; ms < 4; ++ms)
#pragma unroll
                for (int ns = 0; ns < 4; ++ns)
#pragma unroll
                    for (int r = 0; r < 4; ++r) {
                        int row2 = ms * 16 + sg * 4 + r;
                        int col = cb * 64 + ns * 16 + ul;
                        hwPart[((size_t)nb * 64 + row2) * 1024 + col] =
                            f2bf(hacc[ms][ns][r]);
                    }
        }
    }
}

// ---------------- final loss over all steps ----------------
__global__ __launch_bounds__(256) void final_loss(
    const float* __restrict__ psumP, const float* __restrict__ tlogs,
    const float* __restrict__ msum, float* __restrict__ out)
{
    __shared__ float sl[16000];
    int s = blockIdx.x, tid = threadIdx.x;
    const float* src = psumP + (size_t)s * 16000;
    for (int i = tid; i < 16000; i += 256) sl[i] = src[i];
    __syncthreads();
    if (tid < 64) {
        float tot = 0.f;
        for (int i = 0; i < 250; ++i) tot += sl[i * 64 + tid];
        float logp = tlogs[s * 64 + tid] - __logf(tot);
        float term = -logp * msum[s] * (1.f / 4096.f);
        for (int off = 32; off; off >>= 1) term += __shfl_down(term, off);
        if (tid == 0) atomicAdd(out, term);
    }
}

// ---------------- host ----------------
extern "C" void kernel_launch(void* const* d_in, const int* in_sizes, int n_in,
                              void* d_out, int out_size, void* d_ws, size_t ws_size,
                              hipStream_t stream)
{
    const float* action_feat = (const float*)d_in[1];
    const float* video_mask  = (const float*)d_in[3];
    const int*   captions    = (const int*)d_in[4];
    const float* capmask     = (const float*)d_in[5];
    const float* enc_img_W   = (const float*)d_in[6];
    const float* enc_img_b   = (const float*)d_in[7];
    const float* enc_mean_W  = (const float*)d_in[8];
    const float* enc_mean_b  = (const float*)d_in[9];
    const float* att_w       = (const float*)d_in[10];
    const float* att_Wa      = (const float*)d_in[11];
    const float* att_Ua      = (const float*)d_in[12];
    const float* att_ba      = (const float*)d_in[13];
    const float* Wemb        = (const float*)d_in[14];
    const float* embW        = (const float*)d_in[15];
    const float* embb        = (const float*)d_in[16];
    const float* W1ih        = (const float*)d_in[17];
    const float* W1hh        = (const float*)d_in[18];
    const float* b1ih        = (const float*)d_in[19];
    const float* b1hh        = (const float*)d_in[20];
    const float* W2ih        = (const float*)d_in[21];
    const float* W2hh        = (const float*)d_in[22];
    const float* b2ih        = (const float*)d_in[23];
    const float* b2hh        = (const float*)d_in[24];

    char* base = (char*)d_ws;
    size_t off = 0;
    auto alloc = [&](size_t bytes) {
        char* p = base + off;
        off = (off + bytes + 255) & ~(size_t)255;
        return p;
    };
    constexpr int BIG = 0x40000000;

    us* vf       = (us*)alloc((size_t)2560 * 1024 * 2);
    us* imgp     = (us*)alloc((size_t)2560 * 1024 * 2);
    float* fm    = (float*)alloc((size_t)64 * 2048 * 4);
    float* hw    = (float*)alloc((size_t)64 * 1024 * 4);
    us* hwPart   = (us*)alloc((size_t)64 * 64 * 1024 * 2);
    float* bsum1 = (float*)alloc(4096 * 4);
    float* bsum2 = (float*)alloc(4096 * 4);
    float* msum  = (float*)alloc(32 * 4);
    float* psumP = (float*)alloc((size_t)kNS * 250 * 64 * 4);
    float* tlogs = (float*)alloc((size_t)kNS * 64 * 4);
    us* Gemb     = (us*)alloc((size_t)kNS * 64 * 4096 * 2);
    us* x2p0 = (us*)alloc((size_t)64 * 2048 * 2);
    us* x2p1 = (us*)alloc((size_t)64 * 2048 * 2);
    float* c1    = (float*)alloc((size_t)64 * 1024 * 4);
    float* c2    = (float*)alloc((size_t)64 * 1024 * 4);
    size_t zlen  = (size_t)((char*)(c2 + 64 * 1024) - (char*)x2p0);

    us* x1p0 = (us*)alloc((size_t)64 * 2048 * 2);
    us* x1p1 = (us*)alloc((size_t)64 * 2048 * 2);
    us* h2hist = (us*)alloc((size_t)(kNS + 1) * 64 * 1024 * 2);
    us* embP = (us*)alloc((size_t)kNS * 64 * 1024 * 2);
    us* afP  = (us*)alloc((size_t)2560 * 2048 * 2);
    us* vfP  = (us*)alloc((size_t)2560 * 1024 * 2);
    us* fmP  = (us*)alloc((size_t)64 * 2048 * 2);
    us* WiP  = (us*)alloc((size_t)2048 * 1024 * 2);
    us* WmP  = (us*)alloc((size_t)2048 * 1024 * 2);
    us* WuaP = (us*)alloc((size_t)1024 * 1024 * 2);
    us* WaP  = (us*)alloc((size_t)1024 * 1024 * 2);
    us* WaE  = (us*)alloc((size_t)64 * 16 * 4 * 512 * 2);
    us* W1p  = (us*)alloc((size_t)3072 * 4096 * 2);
    us* W2p  = (us*)alloc((size_t)2048 * 4096 * 2);
    us* WvP  = (us*)alloc((size_t)1024 * 32000 * 2);
    if (off > ws_size) return;

    hipMemsetAsync(d_out, 0, 4, stream);
    hipMemsetAsync(x2p0, 0, zlen, stream);

    prep_mean<<<97, 256, 0, stream>>>(action_feat, fm, b1ih, b1hh, b2ih, b2hh,
                                      capmask, bsum1, bsum2, msum);
    pack_rm<<<dim3(16, 4), 256, 0, stream>>>(fm, 2048, BIG, nullptr, 0,
                                             4, 16, 64, 64, fmP);
    pack_rm<<<dim3(16, 160), 256, 0, stream>>>(action_feat, 2048, BIG, nullptr, 0,
                                               4, 16, 64, 64, afP);
    pack_rm<<<dim3(24, 256), 256, 0, stream>>>(W1ih, 2048, 2048, W1hh, 1024,
                                               4, 1024, 16, 96, W1p);
    pack_rm<<<dim3(16, 256), 256, 0, stream>>>(W2ih, 1024, 1024, W2hh, 1024,
                                               4, 1024, 16, 64, W2p);
    pack_sm4<<<1536, 256, 0, stream>>>(enc_img_W, enc_mean_W, att_Ua, att_Wa,
                                       WiP, WmP, WuaP, WaP);
    pack_wae<<<1024, 256, 0, stream>>>(att_Wa, WaE);
    pack_cm<<<dim3(250, 32), 256, 0, stream>>>(embW, WvP);
    pack_emb<<<960, 256, 0, stream>>>(Wemb, captions, embP);

    enc_gemm<64><<<dim3(16, 40), 256, 0, stream>>>(afP, WiP, enc_img_b, vf, vfP);
    p3_gemm<<<16, 256, 0, stream>>>(fmP, WmP, enc_mean_b, x1p0, h2hist);
    enc_gemm<32><<<dim3(16, 40), 256, 0, stream>>>(vfP, WuaP, att_ba, imgp, nullptr);
    gemb_gemm<<<1920, 256, 0, stream>>>(embP, W1p, Gemb);
    hwa_gemm<<<16, 512, 0, stream>>>(h2hist, WaP, hw);   // s=0 only

    int issued = 0;
    for (int s = 0; s < kNS; ++s) {
        us* x1c = (s & 1) ? x1p1 : x1p0;
        us* x1n = (s & 1) ? x1p0 : x1p1;
        us* x2c = (s & 1) ? x2p1 : x2p0;
        us* x2n = (s & 1) ? x2p0 : x2p1;
        int ready = (s >= 3) ? 250 * ((s - 3) / 3 + 1) : 0;
        int cnt = ready - issued;
        if (cnt > 84) cnt = 84;
        if (cnt < 0) cnt = 0;
        attn_logits<<<64 + cnt, 256, 0, stream>>>(
            (s == 0) ? hw : nullptr, hwPart, imgp, att_w, vf, video_mask, x1c,
            h2hist, WvP, embb, captions, psumP, tlogs, issued);
        issued += cnt;
        gates_cell<64, 96, 32><<<64, 1024, 0, stream>>>(
            x1c, W1p, bsum1, Gemb + (size_t)s * 64 * 4096, c1,
            x1n, 1024, x2c, 0);
        gates2_cell<<<64, 1024, 0, stream>>>(
            x2c, W2p, bsum2, c2,
            x2n, 1024, h2hist + (size_t)(s + 1) * 65536, 0,
            (s < kNS - 1) ? hwPart : nullptr, WaE);
    }
    int rem = 2500 - issued;
    logits_tail<<<rem, 256, 0, stream>>>(h2hist, WvP, embb, captions,
                                         psumP, tlogs, issued);
    final_loss<<<kNS, 256, 0, stream>>>(psumP, tlogs, msum, (float*)d_out);
}